// Round 1
// baseline (2476.912 us; speedup 1.0000x reference)
//
#include <hip/hip_runtime.h>
#include <stdint.h>

// ---- problem constants ----
#define NB 16        // batch
#define NN 4096      // nodes
#define DD 64        // feature dim (== S)
#define EE 32768     // edges (before self loops)
#define ETOT 36864   // edges + self loops
#define ROWS 65536   // B*N

typedef _Float16 f16;
typedef f16   half8 __attribute__((ext_vector_type(8)));
typedef f16   f16x8 __attribute__((ext_vector_type(8)));
typedef float f32x4 __attribute__((ext_vector_type(4)));

__device__ __forceinline__ void gload16(const f16* g, f16* l) {
  __builtin_amdgcn_global_load_lds((const __attribute__((address_space(1))) void*)g,
                                   (__attribute__((address_space(3))) void*)l, 16, 0, 0);
}

// ---------------- CSR build ----------------
__global__ __launch_bounds__(256) void k_zero(int* p, int n) {
  int i = blockIdx.x * 256 + threadIdx.x;
  if (i < n) p[i] = 0;
}

__global__ __launch_bounds__(256) void k_count(const int* __restrict__ ei, int* __restrict__ cnt) {
  int t = blockIdx.x * 256 + threadIdx.x;
  if (t >= ETOT) return;
  int d = (t < EE) ? ei[EE + t] : (t - EE);
  atomicAdd(&cnt[d], 1);
}

__global__ __launch_bounds__(256) void k_scan(const int* __restrict__ cnt, int* __restrict__ offs) {
  __shared__ int part[256];
  int t = threadIdx.x;
  int loc[16]; int s = 0;
  #pragma unroll
  for (int i = 0; i < 16; ++i) { int v = cnt[(t << 4) + i]; loc[i] = s; s += v; }
  part[t] = s;
  __syncthreads();
  int own = s;
  for (int d = 1; d < 256; d <<= 1) {
    int u = (t >= d) ? part[t - d] : 0;
    __syncthreads();
    part[t] += u;
    __syncthreads();
  }
  int base = part[t] - own;
  #pragma unroll
  for (int i = 0; i < 16; ++i) offs[(t << 4) + i] = base + loc[i];
}

__global__ __launch_bounds__(256) void k_fill(const int* __restrict__ ei, const int* __restrict__ offs,
                                              int* __restrict__ cur, int* __restrict__ esrc) {
  int t = blockIdx.x * 256 + threadIdx.x;
  if (t >= ETOT) return;
  int s, d;
  if (t < EE) { s = ei[t]; d = ei[EE + t]; } else { s = d = t - EE; }
  int p = atomicAdd(&cur[d], 1);
  esrc[offs[d] + p] = s;
}

// ---------------- seq_linear: h = in^T @ Wseq + b + in^T ----------------
__global__ __launch_bounds__(256) void k_seq(const float* __restrict__ inp, const float* __restrict__ Wseq,
                                             const float* __restrict__ bseq, float* __restrict__ h) {
  __shared__ float X[64 * 68];
  int t = threadIdx.x;
  int b = blockIdx.x >> 6, n0 = (blockIdx.x & 63) << 6;
  #pragma unroll
  for (int i = 0; i < 16; ++i) {
    int idx = t + (i << 8);
    int s = idx >> 6, nl = idx & 63;
    X[nl * 68 + s] = inp[((size_t)((b << 6) + s) << 12) + n0 + nl];
  }
  __syncthreads();
  int c = t & 63, rg = t >> 6;
  float Wc[64];
  #pragma unroll
  for (int k = 0; k < 64; ++k) Wc[k] = Wseq[(k << 6) + c];
  float bc = bseq[c];
  for (int rr = 0; rr < 16; ++rr) {
    int r = (rg << 4) + rr;
    float a = bc + X[r * 68 + c];
    #pragma unroll
    for (int k4 = 0; k4 < 16; ++k4) {
      float4 x = *(const float4*)&X[r * 68 + (k4 << 2)];
      a = fmaf(x.x, Wc[4*k4+0], a); a = fmaf(x.y, Wc[4*k4+1], a);
      a = fmaf(x.z, Wc[4*k4+2], a); a = fmaf(x.w, Wc[4*k4+3], a);
    }
    h[((size_t)(b << 12) + n0 + r) * 64 + c] = a;
  }
}

// ---------------- transpose h [ (b,n), d ] -> HT f16 [ (b,d), n ] ----------------
__global__ __launch_bounds__(256) void k_tr(const float* __restrict__ h, f16* __restrict__ HT) {
  __shared__ float X[64 * 68];
  int t = threadIdx.x;
  int b = blockIdx.x >> 6, n0 = (blockIdx.x & 63) << 6;
  #pragma unroll
  for (int i = 0; i < 16; ++i) {
    int idx = t + (i << 8);
    int nl = idx >> 6, d = idx & 63;
    X[nl * 68 + d] = h[((size_t)(b << 12) + n0 + nl) * 64 + d];
  }
  __syncthreads();
  int nl = t & 63, dg = t >> 6;
  #pragma unroll
  for (int i = 0; i < 16; ++i) {
    int d = (dg << 4) + i;
    HT[((size_t)((b << 6) + d) << 12) + n0 + nl] = (f16)X[nl * 68 + d];
  }
}

// ---------------- adjacency: raw relu(SE@TE) -> A(f16), row max / inv-sum ----------------
__global__ __launch_bounds__(256) void k_adj(const float* __restrict__ SE, const float* __restrict__ TE,
                                             f16* __restrict__ A, float* __restrict__ rowM,
                                             float* __restrict__ rowZ) {
  __shared__ float SEl[1024];
  __shared__ float TEt[256 * 68];
  __shared__ float Mred[256], Zred[256];
  __shared__ float Mrow[16], Zinv[16];
  int t = threadIdx.x;
  int m0 = blockIdx.x << 4;
  #pragma unroll
  for (int i = 0; i < 4; ++i) SEl[t + (i << 8)] = SE[((size_t)m0 << 6) + t + (i << 8)];
  float mth[16], zth[16], v[16];
  #pragma unroll
  for (int r = 0; r < 16; ++r) { mth[r] = -1e30f; zth[r] = 0.f; }
  for (int jt = 0; jt < 16; ++jt) {
    __syncthreads();
    #pragma unroll
    for (int i = 0; i < 64; ++i) {
      int idx = t + (i << 8);
      TEt[(idx & 255) * 68 + (idx >> 8)] = TE[((size_t)(idx >> 8) << 12) + (jt << 8) + (idx & 255)];
    }
    __syncthreads();
    #pragma unroll
    for (int r = 0; r < 16; ++r) v[r] = 0.f;
    #pragma unroll
    for (int k4 = 0; k4 < 16; ++k4) {
      float4 te = *(const float4*)&TEt[t * 68 + (k4 << 2)];
      #pragma unroll
      for (int r = 0; r < 16; ++r) {
        float4 se = *(const float4*)&SEl[(r << 6) + (k4 << 2)];
        float a = v[r];
        a = fmaf(te.x, se.x, a); a = fmaf(te.y, se.y, a);
        a = fmaf(te.z, se.z, a); a = fmaf(te.w, se.w, a);
        v[r] = a;
      }
    }
    #pragma unroll
    for (int r = 0; r < 16; ++r) {
      float vv = fmaxf(v[r], 0.f);
      A[((size_t)(m0 + r) << 12) + (jt << 8) + t] = (f16)vv;   // raw logits (softmax applied later)
      if (vv > mth[r]) { zth[r] = zth[r] * __expf(mth[r] - vv) + 1.f; mth[r] = vv; }
      else zth[r] += __expf(vv - mth[r]);
    }
  }
  // reduce per-row (m,z) across 256 threads
  __syncthreads();
  float* mbuf = TEt;
  float* zbuf = TEt + 4096;
  #pragma unroll
  for (int r = 0; r < 16; ++r) { mbuf[(r << 8) + t] = mth[r]; zbuf[(r << 8) + t] = zth[r]; }
  __syncthreads();
  {
    int r = t >> 4, sg = t & 15;
    float m = -1e30f, z = 0.f;
    for (int i = 0; i < 16; ++i) {
      float mm = mbuf[(r << 8) + (sg << 4) + i];
      float zz = zbuf[(r << 8) + (sg << 4) + i];
      if (mm > m) { z = z * __expf(m - mm) + zz; m = mm; }
      else z += zz * __expf(mm - m);
    }
    Mred[(r << 4) + sg] = m; Zred[(r << 4) + sg] = z;
  }
  __syncthreads();
  if (t < 16) {
    float m = -1e30f, z = 0.f;
    for (int i = 0; i < 16; ++i) {
      float mm = Mred[(t << 4) + i], zz = Zred[(t << 4) + i];
      if (mm > m) { z = z * __expf(m - mm) + zz; m = mm; }
      else z += zz * __expf(mm - m);
    }
    rowM[m0 + t] = m;
    rowZ[m0 + t] = 1.f / z;
  }
}

__global__ __launch_bounds__(256) void k_smaxA(f16* __restrict__ A, const float* __restrict__ rowM,
                                               const float* __restrict__ rowZ) {
  size_t base = ((size_t)blockIdx.x * 256 + threadIdx.x) * 8;
  int row = (int)(base >> 12);
  float m = rowM[row], zi = rowZ[row];
  f16x8 v = *(const f16x8*)(A + base);
  #pragma unroll
  for (int i = 0; i < 8; ++i) v[i] = (f16)(__expf((float)v[i] - m) * zi);
  *(f16x8*)(A + base) = v;
}

// ---------------- big GEMM: C[m, j] = sum_k A[m,k] * BT[j,k]; k-split via blockIdx.z ----------------
__global__ __launch_bounds__(256) void k_gemm(const f16* __restrict__ A, const f16* __restrict__ BT,
                                              float* __restrict__ Cout) {
  __shared__ f16 Al[128 * 32];
  __shared__ f16 Bl[128 * 32];
  const int t = threadIdx.x, lane = t & 63, w = t >> 6;
  const int m0 = blockIdx.y << 7, j0 = blockIdx.x << 7;
  const int kbase = blockIdx.z << 11;
  float* __restrict__ C = Cout + ((size_t)blockIdx.z << 22);
  const int l15 = lane & 15, lhi = lane >> 4;
  const int wm = (w >> 1) << 6, wj = (w & 1) << 6;
  f32x4 acc[4][4] = {};
  const int c0 = (w << 6) + lane;
  const int row0 = c0 >> 2, ko0 = (c0 & 3) << 3;
  const int c1 = c0 + 256;
  const int row1 = c1 >> 2, ko1 = (c1 & 3) << 3;
  const f16* ga0 = A  + (size_t)(m0 + row0) * 4096 + kbase + ko0;
  const f16* ga1 = A  + (size_t)(m0 + row1) * 4096 + kbase + ko1;
  const f16* gb0 = BT + (size_t)(j0 + row0) * 4096 + kbase + ko0;
  const f16* gb1 = BT + (size_t)(j0 + row1) * 4096 + kbase + ko1;
  f16* la0 = Al + c0 * 8; f16* la1 = Al + c1 * 8;
  f16* lb0 = Bl + c0 * 8; f16* lb1 = Bl + c1 * 8;
  for (int kt = 0; kt < 64; ++kt) {
    const int kof = kt << 5;
    gload16(ga0 + kof, la0);
    gload16(ga1 + kof, la1);
    gload16(gb0 + kof, lb0);
    gload16(gb1 + kof, lb1);
    __syncthreads();
    half8 af[4], bf[4];
    #pragma unroll
    for (int i = 0; i < 4; ++i) {
      af[i] = *(const half8*)(Al + (wm + i * 16 + l15) * 32 + lhi * 8);
      bf[i] = *(const half8*)(Bl + (wj + i * 16 + l15) * 32 + lhi * 8);
    }
    #pragma unroll
    for (int mi = 0; mi < 4; ++mi)
      #pragma unroll
      for (int nj = 0; nj < 4; ++nj)
        acc[mi][nj] = __builtin_amdgcn_mfma_f32_16x16x32_f16(af[mi], bf[nj], acc[mi][nj], 0, 0, 0);
    __syncthreads();
  }
  #pragma unroll
  for (int mi = 0; mi < 4; ++mi)
    #pragma unroll
    for (int nj = 0; nj < 4; ++nj)
      #pragma unroll
      for (int r = 0; r < 4; ++r) {
        int row = m0 + wm + mi * 16 + lhi * 4 + r;
        int col = j0 + wj + nj * 16 + l15;
        C[(size_t)row * 1024 + col] = acc[mi][nj][r];
      }
}

// ---------------- xp = h @ Wg  (f16 out) ----------------
template<int H>
__global__ __launch_bounds__(256) void k_xp(const float* __restrict__ h, const float* __restrict__ Wg,
                                            f16* __restrict__ xp) {
  __shared__ float X[64 * 68];
  int t = threadIdx.x;
  size_t r0 = (size_t)blockIdx.x << 6;
  #pragma unroll
  for (int i = 0; i < 16; ++i) {
    int idx = t + (i << 8);
    int nl = idx >> 6, d = idx & 63;
    X[nl * 68 + d] = h[(r0 + nl) * 64 + d];
  }
  __syncthreads();
  int c = t & 63, rg = t >> 6;
  for (int hh = 0; hh < H; ++hh) {
    float Wc[64];
    #pragma unroll
    for (int k = 0; k < 64; ++k) Wc[k] = Wg[k * (H * 64) + (hh << 6) + c];
    for (int rr = 0; rr < 16; ++rr) {
      int r = (rg << 4) + rr;
      float a = 0.f;
      #pragma unroll
      for (int k4 = 0; k4 < 16; ++k4) {
        float4 x = *(const float4*)&X[r * 68 + (k4 << 2)];
        a = fmaf(x.x, Wc[4*k4+0], a); a = fmaf(x.y, Wc[4*k4+1], a);
        a = fmaf(x.z, Wc[4*k4+2], a); a = fmaf(x.w, Wc[4*k4+3], a);
      }
      xp[(r0 + r) * (H * 64) + (hh << 6) + c] = (f16)a;
    }
  }
}

// ---------------- attention dots: als/ald = xp . a_src/a_dst ----------------
template<int H>
__global__ __launch_bounds__(256) void k_dots(const f16* __restrict__ xp, const float* __restrict__ asrc,
                                              const float* __restrict__ adst,
                                              float* __restrict__ als, float* __restrict__ ald) {
  int t = threadIdx.x, lane = t & 63;
  size_t r = ((size_t)blockIdx.x << 2) + (t >> 6);
  const f16* row = xp + r * (H * 64);
  #pragma unroll
  for (int hh = 0; hh < H; ++hh) {
    float v = (float)row[(hh << 6) + lane];
    float a = v * asrc[(hh << 6) + lane];
    float d = v * adst[(hh << 6) + lane];
    #pragma unroll
    for (int s = 32; s; s >>= 1) { a += __shfl_xor(a, s); d += __shfl_xor(d, s); }
    if (lane == 0) { als[r * H + hh] = a; ald[r * H + hh] = d; }
  }
}

// ---------------- GAT aggregation: one wave per (b, node) ----------------
template<int H>
__global__ __launch_bounds__(256) void k_agg(const f16* __restrict__ xp, const float* __restrict__ als,
                                             const float* __restrict__ ald,
                                             const int* __restrict__ offs, const int* __restrict__ cnt,
                                             const int* __restrict__ esrc, const float* __restrict__ bg,
                                             float* __restrict__ hcur) {
  int t = threadIdx.x, lane = t & 63;
  int wid = (blockIdx.x << 2) + (t >> 6);
  int b = wid >> 12, n = wid & 4095;
  size_t rbase = (size_t)b << 12;
  int o = offs[n], c = cnt[n];
  float aldh[H], mh[H], zh[H];
  #pragma unroll
  for (int hh = 0; hh < H; ++hh) { aldh[hh] = ald[(rbase + n) * H + hh]; mh[hh] = -1e30f; zh[hh] = 0.f; }
  for (int e = 0; e < c; ++e) {
    int s = esrc[o + e];
    #pragma unroll
    for (int hh = 0; hh < H; ++hh) {
      float ev = als[(rbase + s) * H + hh] + aldh[hh];
      ev = ev > 0.f ? ev : 0.2f * ev;
      if (ev > mh[hh]) { zh[hh] = zh[hh] * __expf(mh[hh] - ev) + 1.f; mh[hh] = ev; }
      else zh[hh] += __expf(ev - mh[hh]);
    }
  }
  float inv[H];
  #pragma unroll
  for (int hh = 0; hh < H; ++hh) inv[hh] = 1.f / zh[hh];
  float acc = 0.f;
  for (int e = 0; e < c; ++e) {
    int s = esrc[o + e];
    #pragma unroll
    for (int hh = 0; hh < H; ++hh) {
      float ev = als[(rbase + s) * H + hh] + aldh[hh];
      ev = ev > 0.f ? ev : 0.2f * ev;
      float al = __expf(ev - mh[hh]) * inv[hh];
      acc = fmaf(al, (float)xp[(rbase + s) * (size_t)(H * 64) + (hh << 6) + lane], acc);
    }
  }
  hcur[(rbase + n) * 64 + lane] = acc * (1.f / H) + bg[lane];
}

// ---------------- layer-0 combine ----------------
__global__ __launch_bounds__(256) void k_comb0(const float* __restrict__ h, const float* __restrict__ adp,
                                               const float* __restrict__ Wl, const float* __restrict__ bl,
                                               const float* __restrict__ Wo, const float* __restrict__ bo,
                                               float* __restrict__ hout) {
  __shared__ float Xa[64 * 68];
  __shared__ float Xh[64 * 68];
  int t = threadIdx.x;
  int b = blockIdx.x >> 6, n0 = (blockIdx.x & 63) << 6;
  #pragma unroll
  for (int i = 0; i < 16; ++i) {
    int idx = t + (i << 8);
    int nl = idx >> 6, d = idx & 63;
    size_t arow = ((size_t)(n0 + nl) << 10) + (b << 6) + d;
    Xa[nl * 68 + d] = adp[arow] + adp[arow + ((size_t)4096 * 1024)];
    Xh[nl * 68 + d] = h[((size_t)(b << 12) + n0 + nl) * 64 + d];
  }
  __syncthreads();
  int c = t & 63, rg = t >> 6;
  float blc = bl[c], boc = bo[c];
  float Wc[64], gv[16];
  #pragma unroll
  for (int k = 0; k < 64; ++k) Wc[k] = Wl[(k << 6) + c];
  for (int rr = 0; rr < 16; ++rr) {
    int r = (rg << 4) + rr;
    float ag = blc;
    #pragma unroll
    for (int k4 = 0; k4 < 16; ++k4) {
      float4 x = *(const float4*)&Xa[r * 68 + (k4 << 2)];
      ag = fmaf(x.x, Wc[4*k4+0], ag); ag = fmaf(x.y, Wc[4*k4+1], ag);
      ag = fmaf(x.z, Wc[4*k4+2], ag); ag = fmaf(x.w, Wc[4*k4+3], ag);
    }
    gv[rr] = 1.f / (1.f + __expf(-ag));
  }
  #pragma unroll
  for (int k = 0; k < 64; ++k) Wc[k] = Wo[(k << 6) + c];
  for (int rr = 0; rr < 16; ++rr) {
    int r = (rg << 4) + rr;
    float ao = boc;
    #pragma unroll
    for (int k4 = 0; k4 < 16; ++k4) {
      float4 x = *(const float4*)&Xh[r * 68 + (k4 << 2)];
      ao = fmaf(x.x, Wc[4*k4+0], ao); ao = fmaf(x.y, Wc[4*k4+1], ao);
      ao = fmaf(x.z, Wc[4*k4+2], ao); ao = fmaf(x.w, Wc[4*k4+3], ao);
    }
    float hv = Xh[r * 68 + c];
    float g = gv[rr];
    hout[((size_t)(b << 12) + n0 + r) * 64 + c] = tanhf(hv) * g + ao * (1.f - g);
  }
}

// ---------------- layer-1/2 combine ----------------
template<int ACT>   // 0: leaky 0.01, 1: relu
__global__ __launch_bounds__(256) void k_comb12(const float* __restrict__ h, const float* __restrict__ adp,
                                                const float* __restrict__ hcur, const float* __restrict__ Wl,
                                                const float* __restrict__ bl, float* __restrict__ hout) {
  __shared__ float Xa[64 * 68];
  int t = threadIdx.x;
  int b = blockIdx.x >> 6, n0 = (blockIdx.x & 63) << 6;
  #pragma unroll
  for (int i = 0; i < 16; ++i) {
    int idx = t + (i << 8);
    int nl = idx >> 6, d = idx & 63;
    size_t arow = ((size_t)(n0 + nl) << 10) + (b << 6) + d;
    Xa[nl * 68 + d] = adp[arow] + adp[arow + ((size_t)4096 * 1024)];
  }
  __syncthreads();
  int c = t & 63, rg = t >> 6;
  float Wc[64];
  #pragma unroll
  for (int k = 0; k < 64; ++k) Wc[k] = Wl[(k << 6) + c];
  float blc = bl[c];
  for (int rr = 0; rr < 16; ++rr) {
    int r = (rg << 4) + rr;
    float ag = blc;
    #pragma unroll
    for (int k4 = 0; k4 < 16; ++k4) {
      float4 x = *(const float4*)&Xa[r * 68 + (k4 << 2)];
      ag = fmaf(x.x, Wc[4*k4+0], ag); ag = fmaf(x.y, Wc[4*k4+1], ag);
      ag = fmaf(x.z, Wc[4*k4+2], ag); ag = fmaf(x.w, Wc[4*k4+3], ag);
    }
    float g = 1.f / (1.f + __expf(-ag));
    size_t ridx = ((size_t)(b << 12) + n0 + r) * 64 + c;
    float hv = h[ridx], cv = hcur[ridx];
    float act = ACT ? fmaxf(cv, 0.f) : (cv > 0.f ? cv : 0.01f * cv);
    hout[ridx] = act * g + hv * (1.f - g);
  }
}

// ---------------- host launch ----------------
extern "C" void kernel_launch(void* const* d_in, const int* in_sizes, int n_in,
                              void* d_out, int out_size, void* d_ws, size_t ws_size,
                              hipStream_t stream) {
  (void)in_sizes; (void)n_in; (void)out_size; (void)ws_size;
  const float* inp  = (const float*)d_in[0];
  const int*   ei   = (const int*)d_in[1];
  const float* Wseq = (const float*)d_in[2];
  const float* bseq = (const float*)d_in[3];
  const float* SE   = (const float*)d_in[4];
  const float* TE   = (const float*)d_in[5];
  const float* Wg[3]   = {(const float*)d_in[6],  (const float*)d_in[12], (const float*)d_in[18]};
  const float* asrc[3] = {(const float*)d_in[7],  (const float*)d_in[13], (const float*)d_in[19]};
  const float* adst[3] = {(const float*)d_in[8],  (const float*)d_in[14], (const float*)d_in[20]};
  const float* bgp[3]  = {(const float*)d_in[9],  (const float*)d_in[15], (const float*)d_in[21]};
  const float* Wl[3]   = {(const float*)d_in[10], (const float*)d_in[16], (const float*)d_in[22]};
  const float* bl[3]   = {(const float*)d_in[11], (const float*)d_in[17], (const float*)d_in[23]};
  const float* Wo = (const float*)d_in[24];
  const float* bo = (const float*)d_in[25];
  float* out = (float*)d_out;

  uint8_t* ws = (uint8_t*)d_ws;
  size_t o = 0;
  auto nxt = [&](size_t sz) { void* p = ws + o; o += (sz + 255) & ~(size_t)255; return p; };
  f16*   Af   = (f16*)  nxt((size_t)NN * NN * sizeof(f16));        // 32 MB
  f16*   HT   = (f16*)  nxt((size_t)1024 * NN * sizeof(f16));      // 8 MB
  float* h    = (float*)nxt((size_t)ROWS * 64 * 4);                // 16 MB
  float* adp  = (float*)nxt((size_t)2 * NN * 1024 * 4);            // 32 MB (2 k-split parts)
  f16*   xp   = (f16*)  nxt((size_t)ROWS * 192 * sizeof(f16));     // 24 MB
  float* als  = (float*)nxt((size_t)ROWS * 3 * 4);
  float* ald  = (float*)nxt((size_t)ROWS * 3 * 4);
  float* hcur = (float*)nxt((size_t)ROWS * 64 * 4);                // 16 MB
  float* rowM = (float*)nxt((size_t)NN * 4);
  float* rowZ = (float*)nxt((size_t)NN * 4);
  int*   cnt  = (int*)  nxt((size_t)NN * 4);
  int*   curp = (int*)  nxt((size_t)NN * 4);
  int*   offs = (int*)  nxt((size_t)NN * 4);
  int*   esrc = (int*)  nxt((size_t)ETOT * 4);

  dim3 blk(256);
  // CSR build
  k_zero<<<16, blk, 0, stream>>>(cnt, NN);
  k_zero<<<16, blk, 0, stream>>>(curp, NN);
  k_count<<<144, blk, 0, stream>>>(ei, cnt);
  k_scan<<<1, blk, 0, stream>>>(cnt, offs);
  k_fill<<<144, blk, 0, stream>>>(ei, offs, curp, esrc);
  // h0 + HT + adjacency
  k_seq<<<1024, blk, 0, stream>>>(inp, Wseq, bseq, h);
  k_tr<<<1024, blk, 0, stream>>>(h, HT);
  k_adj<<<256, blk, 0, stream>>>(SE, TE, Af, rowM, rowZ);
  k_smaxA<<<8192, blk, 0, stream>>>(Af, rowM, rowZ);
  // ---- layer 0 ----
  k_gemm<<<dim3(8, 32, 2), blk, 0, stream>>>(Af, HT, adp);
  k_comb0<<<1024, blk, 0, stream>>>(h, adp, Wl[0], bl[0], Wo, bo, h);
  k_tr<<<1024, blk, 0, stream>>>(h, HT);
  // ---- layer 1 ----
  k_xp<3><<<1024, blk, 0, stream>>>(h, Wg[1], xp);
  k_dots<3><<<16384, blk, 0, stream>>>(xp, asrc[1], adst[1], als, ald);
  k_gemm<<<dim3(8, 32, 2), blk, 0, stream>>>(Af, HT, adp);
  k_agg<3><<<16384, blk, 0, stream>>>(xp, als, ald, offs, cnt, esrc, bgp[1], hcur);
  k_comb12<0><<<1024, blk, 0, stream>>>(h, adp, hcur, Wl[1], bl[1], h);
  k_tr<<<1024, blk, 0, stream>>>(h, HT);
  // ---- layer 2 ----
  k_xp<1><<<1024, blk, 0, stream>>>(h, Wg[2], xp);
  k_dots<1><<<16384, blk, 0, stream>>>(xp, asrc[2], adst[2], als, ald);
  k_gemm<<<dim3(8, 32, 2), blk, 0, stream>>>(Af, HT, adp);
  k_agg<1><<<16384, blk, 0, stream>>>(xp, als, ald, offs, cnt, esrc, bgp[2], hcur);
  k_comb12<1><<<1024, blk, 0, stream>>>(h, adp, hcur, Wl[2], bl[2], out);
}

// Round 2
// 706.311 us; speedup vs baseline: 3.5068x; 3.5068x over previous
//
#include <hip/hip_runtime.h>
#include <stdint.h>

// ---- problem constants ----
#define NB 16        // batch
#define NN 4096      // nodes
#define DD 64        // feature dim (== S)
#define EE 32768     // edges (before self loops)
#define ETOT 36864   // edges + self loops
#define ROWS 65536   // B*N

typedef _Float16 f16;
typedef f16   half8 __attribute__((ext_vector_type(8)));
typedef f16   f16x8 __attribute__((ext_vector_type(8)));
typedef float f32x4 __attribute__((ext_vector_type(4)));

__device__ __forceinline__ void gload16(const f16* g, f16* l) {
  __builtin_amdgcn_global_load_lds((const __attribute__((address_space(1))) void*)g,
                                   (__attribute__((address_space(3))) void*)l, 16, 0, 0);
}

// ---------------- CSR build ----------------
__global__ __launch_bounds__(256) void k_zero(int* p, int n) {
  int i = blockIdx.x * 256 + threadIdx.x;
  if (i < n) p[i] = 0;
}

__global__ __launch_bounds__(256) void k_count(const int* __restrict__ ei, int* __restrict__ cnt) {
  int t = blockIdx.x * 256 + threadIdx.x;
  if (t >= ETOT) return;
  int d = (t < EE) ? ei[EE + t] : (t - EE);
  atomicAdd(&cnt[d], 1);
}

__global__ __launch_bounds__(256) void k_scan(const int* __restrict__ cnt, int* __restrict__ offs) {
  __shared__ int part[256];
  int t = threadIdx.x;
  int loc[16]; int s = 0;
  #pragma unroll
  for (int i = 0; i < 16; ++i) { int v = cnt[(t << 4) + i]; loc[i] = s; s += v; }
  part[t] = s;
  __syncthreads();
  int own = s;
  for (int d = 1; d < 256; d <<= 1) {
    int u = (t >= d) ? part[t - d] : 0;
    __syncthreads();
    part[t] += u;
    __syncthreads();
  }
  int base = part[t] - own;
  #pragma unroll
  for (int i = 0; i < 16; ++i) offs[(t << 4) + i] = base + loc[i];
}

__global__ __launch_bounds__(256) void k_fill(const int* __restrict__ ei, const int* __restrict__ offs,
                                              int* __restrict__ cur, int* __restrict__ esrc) {
  int t = blockIdx.x * 256 + threadIdx.x;
  if (t >= ETOT) return;
  int s, d;
  if (t < EE) { s = ei[t]; d = ei[EE + t]; } else { s = d = t - EE; }
  int p = atomicAdd(&cur[d], 1);
  esrc[offs[d] + p] = s;
}

// ---------------- seq_linear: h = in^T @ Wseq + b + in^T ----------------
__global__ __launch_bounds__(256) void k_seq(const float* __restrict__ inp, const float* __restrict__ Wseq,
                                             const float* __restrict__ bseq, float* __restrict__ h) {
  __shared__ float X[64 * 68];
  int t = threadIdx.x;
  int b = blockIdx.x >> 6, n0 = (blockIdx.x & 63) << 6;
  #pragma unroll
  for (int i = 0; i < 16; ++i) {
    int idx = t + (i << 8);
    int s = idx >> 6, nl = idx & 63;
    X[nl * 68 + s] = inp[((size_t)((b << 6) + s) << 12) + n0 + nl];
  }
  __syncthreads();
  int c = t & 63, rg = t >> 6;
  float Wc[64];
  #pragma unroll
  for (int k = 0; k < 64; ++k) Wc[k] = Wseq[(k << 6) + c];
  float bc = bseq[c];
  for (int rr = 0; rr < 16; ++rr) {
    int r = (rg << 4) + rr;
    float a = bc + X[r * 68 + c];
    #pragma unroll
    for (int k4 = 0; k4 < 16; ++k4) {
      float4 x = *(const float4*)&X[r * 68 + (k4 << 2)];
      a = fmaf(x.x, Wc[4*k4+0], a); a = fmaf(x.y, Wc[4*k4+1], a);
      a = fmaf(x.z, Wc[4*k4+2], a); a = fmaf(x.w, Wc[4*k4+3], a);
    }
    h[((size_t)(b << 12) + n0 + r) * 64 + c] = a;
  }
}

// ---------------- transpose h [ (b,n), d ] -> HT f16 [ (b,d), n ] ----------------
__global__ __launch_bounds__(256) void k_tr(const float* __restrict__ h, f16* __restrict__ HT) {
  __shared__ float X[64 * 68];
  int t = threadIdx.x;
  int b = blockIdx.x >> 6, n0 = (blockIdx.x & 63) << 6;
  #pragma unroll
  for (int i = 0; i < 16; ++i) {
    int idx = t + (i << 8);
    int nl = idx >> 6, d = idx & 63;
    X[nl * 68 + d] = h[((size_t)(b << 12) + n0 + nl) * 64 + d];
  }
  __syncthreads();
  int nl = t & 63, dg = t >> 6;
  #pragma unroll
  for (int i = 0; i < 16; ++i) {
    int d = (dg << 4) + i;
    HT[((size_t)((b << 6) + d) << 12) + n0 + nl] = (f16)X[nl * 68 + d];
  }
}

// ---------------- adjacency prep: casts ----------------
__global__ __launch_bounds__(256) void k_castSE(const float* __restrict__ SE, f16* __restrict__ SEh) {
  int i = (blockIdx.x * 256 + threadIdx.x) * 4;
  float4 v = *(const float4*)(SE + i);
  f16 o[4] = {(f16)v.x, (f16)v.y, (f16)v.z, (f16)v.w};
  *(uint64_t*)(SEh + i) = *(uint64_t*)o;
}

__global__ __launch_bounds__(256) void k_castTE(const float* __restrict__ TE, f16* __restrict__ TEh) {
  __shared__ float X[64 * 65];
  int t = threadIdx.x;
  int j0 = blockIdx.x << 6;
  #pragma unroll
  for (int i = 0; i < 16; ++i) {
    int idx = t + (i << 8);           // 0..4095 = 64k x 64j
    int k = idx >> 6, jl = idx & 63;
    X[jl * 65 + k] = TE[((size_t)k << 12) + j0 + jl];
  }
  __syncthreads();
  int jl = t >> 2, kg = t & 3;        // 4 threads per output row, 16 k each
  f16 o[16];
  #pragma unroll
  for (int i = 0; i < 16; ++i) o[i] = (f16)X[jl * 65 + (kg << 4) + i];
  f16* dst = TEh + ((size_t)(j0 + jl) << 6) + (kg << 4);
  *(uint64_t*)(dst + 0) = *(uint64_t*)(o + 0);
  *(uint64_t*)(dst + 4) = *(uint64_t*)(o + 4);
  *(uint64_t*)(dst + 8) = *(uint64_t*)(o + 8);
  *(uint64_t*)(dst + 12) = *(uint64_t*)(o + 12);
}

// ---------------- adjacency MFMA GEMM: A = exp(relu(SEh @ TEh^T)), row partial sums ----------------
__global__ __launch_bounds__(256) void k_adjmm(const f16* __restrict__ SEh, const f16* __restrict__ TEh,
                                               f16* __restrict__ A, float* __restrict__ Zpart) {
  __shared__ f16 Al[128 * 32];
  __shared__ f16 Bl[128 * 32];
  const int t = threadIdx.x, lane = t & 63, w = t >> 6;
  const int m0 = blockIdx.y << 7, j0 = blockIdx.x << 7;
  const int l15 = lane & 15, lhi = lane >> 4;
  const int wm = (w >> 1) << 6, wj = (w & 1) << 6;
  f32x4 acc[4][4] = {};
  const int c0 = (w << 6) + lane;
  const int row0 = c0 >> 2, ko0 = (c0 & 3) << 3;
  const int c1 = c0 + 256;
  const int row1 = c1 >> 2, ko1 = (c1 & 3) << 3;
  const f16* ga0 = SEh + (size_t)(m0 + row0) * 64 + ko0;
  const f16* ga1 = SEh + (size_t)(m0 + row1) * 64 + ko1;
  const f16* gb0 = TEh + (size_t)(j0 + row0) * 64 + ko0;
  const f16* gb1 = TEh + (size_t)(j0 + row1) * 64 + ko1;
  f16* la0 = Al + c0 * 8; f16* la1 = Al + c1 * 8;
  f16* lb0 = Bl + c0 * 8; f16* lb1 = Bl + c1 * 8;
  for (int kt = 0; kt < 2; ++kt) {
    const int kof = kt << 5;
    gload16(ga0 + kof, la0);
    gload16(ga1 + kof, la1);
    gload16(gb0 + kof, lb0);
    gload16(gb1 + kof, lb1);
    __syncthreads();
    half8 af[4], bf[4];
    #pragma unroll
    for (int i = 0; i < 4; ++i) {
      af[i] = *(const half8*)(Al + (wm + i * 16 + l15) * 32 + lhi * 8);
      bf[i] = *(const half8*)(Bl + (wj + i * 16 + l15) * 32 + lhi * 8);
    }
    #pragma unroll
    for (int mi = 0; mi < 4; ++mi)
      #pragma unroll
      for (int nj = 0; nj < 4; ++nj)
        acc[mi][nj] = __builtin_amdgcn_mfma_f32_16x16x32_f16(af[mi], bf[nj], acc[mi][nj], 0, 0, 0);
    __syncthreads();
  }
  // epilogue: e = exp(relu(.)), store f16, accumulate per-row partial sums
  float rs[4][4];
  #pragma unroll
  for (int mi = 0; mi < 4; ++mi)
    #pragma unroll
    for (int r = 0; r < 4; ++r) rs[mi][r] = 0.f;
  #pragma unroll
  for (int mi = 0; mi < 4; ++mi)
    #pragma unroll
    for (int nj = 0; nj < 4; ++nj)
      #pragma unroll
      for (int r = 0; r < 4; ++r) {
        int row = m0 + wm + mi * 16 + lhi * 4 + r;
        int col = j0 + wj + nj * 16 + l15;
        float e = __expf(fmaxf(acc[mi][nj][r], 0.f));
        f16 eh = (f16)e;
        A[((size_t)row << 12) + col] = eh;
        rs[mi][r] += (float)eh;      // sum the rounded value for consistency
      }
  #pragma unroll
  for (int mi = 0; mi < 4; ++mi)
    #pragma unroll
    for (int r = 0; r < 4; ++r) {
      float s = rs[mi][r];
      s += __shfl_xor(s, 1); s += __shfl_xor(s, 2);
      s += __shfl_xor(s, 4); s += __shfl_xor(s, 8);
      rs[mi][r] = s;
    }
  if (l15 == 0) {
    int p = (blockIdx.x << 1) + (w & 1);
    #pragma unroll
    for (int mi = 0; mi < 4; ++mi)
      #pragma unroll
      for (int r = 0; r < 4; ++r)
        Zpart[((size_t)p << 12) + m0 + wm + mi * 16 + lhi * 4 + r] = rs[mi][r];
  }
}

__global__ __launch_bounds__(256) void k_rowz(const float* __restrict__ Zpart, float* __restrict__ rowZ) {
  int row = blockIdx.x * 256 + threadIdx.x;
  float s = 0.f;
  #pragma unroll 8
  for (int p = 0; p < 64; ++p) s += Zpart[((size_t)p << 12) + row];
  rowZ[row] = 1.f / s;
}

__global__ __launch_bounds__(256) void k_scaleA(f16* __restrict__ A, const float* __restrict__ rowZ) {
  size_t base = ((size_t)blockIdx.x * 256 + threadIdx.x) * 8;
  float zi = rowZ[base >> 12];
  f16x8 v = *(const f16x8*)(A + base);
  #pragma unroll
  for (int i = 0; i < 8; ++i) v[i] = (f16)((float)v[i] * zi);
  *(f16x8*)(A + base) = v;
}

// ---------------- big GEMM: C[m, j] = sum_k A[m,k] * BT[j,k]; k-split via blockIdx.z ----------------
__global__ __launch_bounds__(256) void k_gemm(const f16* __restrict__ A, const f16* __restrict__ BT,
                                              float* __restrict__ Cout) {
  __shared__ f16 Al[128 * 32];
  __shared__ f16 Bl[128 * 32];
  const int t = threadIdx.x, lane = t & 63, w = t >> 6;
  const int m0 = blockIdx.y << 7, j0 = blockIdx.x << 7;
  const int kbase = blockIdx.z << 11;
  float* __restrict__ C = Cout + ((size_t)blockIdx.z << 22);
  const int l15 = lane & 15, lhi = lane >> 4;
  const int wm = (w >> 1) << 6, wj = (w & 1) << 6;
  f32x4 acc[4][4] = {};
  const int c0 = (w << 6) + lane;
  const int row0 = c0 >> 2, ko0 = (c0 & 3) << 3;
  const int c1 = c0 + 256;
  const int row1 = c1 >> 2, ko1 = (c1 & 3) << 3;
  const f16* ga0 = A  + (size_t)(m0 + row0) * 4096 + kbase + ko0;
  const f16* ga1 = A  + (size_t)(m0 + row1) * 4096 + kbase + ko1;
  const f16* gb0 = BT + (size_t)(j0 + row0) * 4096 + kbase + ko0;
  const f16* gb1 = BT + (size_t)(j0 + row1) * 4096 + kbase + ko1;
  f16* la0 = Al + c0 * 8; f16* la1 = Al + c1 * 8;
  f16* lb0 = Bl + c0 * 8; f16* lb1 = Bl + c1 * 8;
  for (int kt = 0; kt < 64; ++kt) {
    const int kof = kt << 5;
    gload16(ga0 + kof, la0);
    gload16(ga1 + kof, la1);
    gload16(gb0 + kof, lb0);
    gload16(gb1 + kof, lb1);
    __syncthreads();
    half8 af[4], bf[4];
    #pragma unroll
    for (int i = 0; i < 4; ++i) {
      af[i] = *(const half8*)(Al + (wm + i * 16 + l15) * 32 + lhi * 8);
      bf[i] = *(const half8*)(Bl + (wj + i * 16 + l15) * 32 + lhi * 8);
    }
    #pragma unroll
    for (int mi = 0; mi < 4; ++mi)
      #pragma unroll
      for (int nj = 0; nj < 4; ++nj)
        acc[mi][nj] = __builtin_amdgcn_mfma_f32_16x16x32_f16(af[mi], bf[nj], acc[mi][nj], 0, 0, 0);
    __syncthreads();
  }
  #pragma unroll
  for (int mi = 0; mi < 4; ++mi)
    #pragma unroll
    for (int nj = 0; nj < 4; ++nj)
      #pragma unroll
      for (int r = 0; r < 4; ++r) {
        int row = m0 + wm + mi * 16 + lhi * 4 + r;
        int col = j0 + wj + nj * 16 + l15;
        C[(size_t)row * 1024 + col] = acc[mi][nj][r];
      }
}

// ---------------- xp = h @ Wg  (f16 out) ----------------
template<int H>
__global__ __launch_bounds__(256) void k_xp(const float* __restrict__ h, const float* __restrict__ Wg,
                                            f16* __restrict__ xp) {
  __shared__ float X[64 * 68];
  int t = threadIdx.x;
  size_t r0 = (size_t)blockIdx.x << 6;
  #pragma unroll
  for (int i = 0; i < 16; ++i) {
    int idx = t + (i << 8);
    int nl = idx >> 6, d = idx & 63;
    X[nl * 68 + d] = h[(r0 + nl) * 64 + d];
  }
  __syncthreads();
  int c = t & 63, rg = t >> 6;
  for (int hh = 0; hh < H; ++hh) {
    float Wc[64];
    #pragma unroll
    for (int k = 0; k < 64; ++k) Wc[k] = Wg[k * (H * 64) + (hh << 6) + c];
    for (int rr = 0; rr < 16; ++rr) {
      int r = (rg << 4) + rr;
      float a = 0.f;
      #pragma unroll
      for (int k4 = 0; k4 < 16; ++k4) {
        float4 x = *(const float4*)&X[r * 68 + (k4 << 2)];
        a = fmaf(x.x, Wc[4*k4+0], a); a = fmaf(x.y, Wc[4*k4+1], a);
        a = fmaf(x.z, Wc[4*k4+2], a); a = fmaf(x.w, Wc[4*k4+3], a);
      }
      xp[(r0 + r) * (H * 64) + (hh << 6) + c] = (f16)a;
    }
  }
}

// ---------------- attention dots: als/ald = xp . a_src/a_dst ----------------
template<int H>
__global__ __launch_bounds__(256) void k_dots(const f16* __restrict__ xp, const float* __restrict__ asrc,
                                              const float* __restrict__ adst,
                                              float* __restrict__ als, float* __restrict__ ald) {
  int t = threadIdx.x, lane = t & 63;
  size_t r = ((size_t)blockIdx.x << 2) + (t >> 6);
  const f16* row = xp + r * (H * 64);
  #pragma unroll
  for (int hh = 0; hh < H; ++hh) {
    float v = (float)row[(hh << 6) + lane];
    float a = v * asrc[(hh << 6) + lane];
    float d = v * adst[(hh << 6) + lane];
    #pragma unroll
    for (int s = 32; s; s >>= 1) { a += __shfl_xor(a, s); d += __shfl_xor(d, s); }
    if (lane == 0) { als[r * H + hh] = a; ald[r * H + hh] = d; }
  }
}

// ---------------- GAT aggregation: one wave per (b, node) ----------------
template<int H>
__global__ __launch_bounds__(256) void k_agg(const f16* __restrict__ xp, const float* __restrict__ als,
                                             const float* __restrict__ ald,
                                             const int* __restrict__ offs, const int* __restrict__ cnt,
                                             const int* __restrict__ esrc, const float* __restrict__ bg,
                                             float* __restrict__ hcur) {
  int t = threadIdx.x, lane = t & 63;
  int wid = (blockIdx.x << 2) + (t >> 6);
  int b = wid >> 12, n = wid & 4095;
  size_t rbase = (size_t)b << 12;
  int o = offs[n], c = cnt[n];
  float aldh[H], mh[H], zh[H];
  #pragma unroll
  for (int hh = 0; hh < H; ++hh) { aldh[hh] = ald[(rbase + n) * H + hh]; mh[hh] = -1e30f; zh[hh] = 0.f; }
  for (int e = 0; e < c; ++e) {
    int s = esrc[o + e];
    #pragma unroll
    for (int hh = 0; hh < H; ++hh) {
      float ev = als[(rbase + s) * H + hh] + aldh[hh];
      ev = ev > 0.f ? ev : 0.2f * ev;
      if (ev > mh[hh]) { zh[hh] = zh[hh] * __expf(mh[hh] - ev) + 1.f; mh[hh] = ev; }
      else zh[hh] += __expf(ev - mh[hh]);
    }
  }
  float inv[H];
  #pragma unroll
  for (int hh = 0; hh < H; ++hh) inv[hh] = 1.f / zh[hh];
  float acc = 0.f;
  for (int e = 0; e < c; ++e) {
    int s = esrc[o + e];
    #pragma unroll
    for (int hh = 0; hh < H; ++hh) {
      float ev = als[(rbase + s) * H + hh] + aldh[hh];
      ev = ev > 0.f ? ev : 0.2f * ev;
      float al = __expf(ev - mh[hh]) * inv[hh];
      acc = fmaf(al, (float)xp[(rbase + s) * (size_t)(H * 64) + (hh << 6) + lane], acc);
    }
  }
  hcur[(rbase + n) * 64 + lane] = acc * (1.f / H) + bg[lane];
}

// ---------------- layer-0 combine ----------------
__global__ __launch_bounds__(256) void k_comb0(const float* __restrict__ h, const float* __restrict__ adp,
                                               const float* __restrict__ Wl, const float* __restrict__ bl,
                                               const float* __restrict__ Wo, const float* __restrict__ bo,
                                               float* __restrict__ hout) {
  __shared__ float Xa[64 * 68];
  __shared__ float Xh[64 * 68];
  int t = threadIdx.x;
  int b = blockIdx.x >> 6, n0 = (blockIdx.x & 63) << 6;
  #pragma unroll
  for (int i = 0; i < 16; ++i) {
    int idx = t + (i << 8);
    int nl = idx >> 6, d = idx & 63;
    size_t arow = ((size_t)(n0 + nl) << 10) + (b << 6) + d;
    Xa[nl * 68 + d] = adp[arow] + adp[arow + ((size_t)4096 * 1024)];
    Xh[nl * 68 + d] = h[((size_t)(b << 12) + n0 + nl) * 64 + d];
  }
  __syncthreads();
  int c = t & 63, rg = t >> 6;
  float blc = bl[c], boc = bo[c];
  float Wc[64], gv[16];
  #pragma unroll
  for (int k = 0; k < 64; ++k) Wc[k] = Wl[(k << 6) + c];
  for (int rr = 0; rr < 16; ++rr) {
    int r = (rg << 4) + rr;
    float ag = blc;
    #pragma unroll
    for (int k4 = 0; k4 < 16; ++k4) {
      float4 x = *(const float4*)&Xa[r * 68 + (k4 << 2)];
      ag = fmaf(x.x, Wc[4*k4+0], ag); ag = fmaf(x.y, Wc[4*k4+1], ag);
      ag = fmaf(x.z, Wc[4*k4+2], ag); ag = fmaf(x.w, Wc[4*k4+3], ag);
    }
    gv[rr] = 1.f / (1.f + __expf(-ag));
  }
  #pragma unroll
  for (int k = 0; k < 64; ++k) Wc[k] = Wo[(k << 6) + c];
  for (int rr = 0; rr < 16; ++rr) {
    int r = (rg << 4) + rr;
    float ao = boc;
    #pragma unroll
    for (int k4 = 0; k4 < 16; ++k4) {
      float4 x = *(const float4*)&Xh[r * 68 + (k4 << 2)];
      ao = fmaf(x.x, Wc[4*k4+0], ao); ao = fmaf(x.y, Wc[4*k4+1], ao);
      ao = fmaf(x.z, Wc[4*k4+2], ao); ao = fmaf(x.w, Wc[4*k4+3], ao);
    }
    float hv = Xh[r * 68 + c];
    float g = gv[rr];
    hout[((size_t)(b << 12) + n0 + r) * 64 + c] = tanhf(hv) * g + ao * (1.f - g);
  }
}

// ---------------- layer-1/2 combine ----------------
template<int ACT>   // 0: leaky 0.01, 1: relu
__global__ __launch_bounds__(256) void k_comb12(const float* __restrict__ h, const float* __restrict__ adp,
                                                const float* __restrict__ hcur, const float* __restrict__ Wl,
                                                const float* __restrict__ bl, float* __restrict__ hout) {
  __shared__ float Xa[64 * 68];
  int t = threadIdx.x;
  int b = blockIdx.x >> 6, n0 = (blockIdx.x & 63) << 6;
  #pragma unroll
  for (int i = 0; i < 16; ++i) {
    int idx = t + (i << 8);
    int nl = idx >> 6, d = idx & 63;
    size_t arow = ((size_t)(n0 + nl) << 10) + (b << 6) + d;
    Xa[nl * 68 + d] = adp[arow] + adp[arow + ((size_t)4096 * 1024)];
  }
  __syncthreads();
  int c = t & 63, rg = t >> 6;
  float Wc[64];
  #pragma unroll
  for (int k = 0; k < 64; ++k) Wc[k] = Wl[(k << 6) + c];
  float blc = bl[c];
  for (int rr = 0; rr < 16; ++rr) {
    int r = (rg << 4) + rr;
    float ag = blc;
    #pragma unroll
    for (int k4 = 0; k4 < 16; ++k4) {
      float4 x = *(const float4*)&Xa[r * 68 + (k4 << 2)];
      ag = fmaf(x.x, Wc[4*k4+0], ag); ag = fmaf(x.y, Wc[4*k4+1], ag);
      ag = fmaf(x.z, Wc[4*k4+2], ag); ag = fmaf(x.w, Wc[4*k4+3], ag);
    }
    float g = 1.f / (1.f + __expf(-ag));
    size_t ridx = ((size_t)(b << 12) + n0 + r) * 64 + c;
    float hv = h[ridx], cv = hcur[ridx];
    float act = ACT ? fmaxf(cv, 0.f) : (cv > 0.f ? cv : 0.01f * cv);
    hout[ridx] = act * g + hv * (1.f - g);
  }
}

// ---------------- host launch ----------------
extern "C" void kernel_launch(void* const* d_in, const int* in_sizes, int n_in,
                              void* d_out, int out_size, void* d_ws, size_t ws_size,
                              hipStream_t stream) {
  (void)in_sizes; (void)n_in; (void)out_size; (void)ws_size;
  const float* inp  = (const float*)d_in[0];
  const int*   ei   = (const int*)d_in[1];
  const float* Wseq = (const float*)d_in[2];
  const float* bseq = (const float*)d_in[3];
  const float* SE   = (const float*)d_in[4];
  const float* TE   = (const float*)d_in[5];
  const float* Wg[3]   = {(const float*)d_in[6],  (const float*)d_in[12], (const float*)d_in[18]};
  const float* asrc[3] = {(const float*)d_in[7],  (const float*)d_in[13], (const float*)d_in[19]};
  const float* adst[3] = {(const float*)d_in[8],  (const float*)d_in[14], (const float*)d_in[20]};
  const float* bgp[3]  = {(const float*)d_in[9],  (const float*)d_in[15], (const float*)d_in[21]};
  const float* Wl[3]   = {(const float*)d_in[10], (const float*)d_in[16], (const float*)d_in[22]};
  const float* bl[3]   = {(const float*)d_in[11], (const float*)d_in[17], (const float*)d_in[23]};
  const float* Wo = (const float*)d_in[24];
  const float* bo = (const float*)d_in[25];
  float* out = (float*)d_out;

  uint8_t* ws = (uint8_t*)d_ws;
  size_t o = 0;
  auto nxt = [&](size_t sz) { void* p = ws + o; o += (sz + 255) & ~(size_t)255; return p; };
  f16*   Af   = (f16*)  nxt((size_t)NN * NN * sizeof(f16));        // 32 MB
  f16*   HT   = (f16*)  nxt((size_t)1024 * NN * sizeof(f16));      // 8 MB
  float* h    = (float*)nxt((size_t)ROWS * 64 * 4);                // 16 MB
  float* adp  = (float*)nxt((size_t)2 * NN * 1024 * 4);            // 32 MB (2 k-split parts)
  f16*   xp   = (f16*)  nxt((size_t)ROWS * 192 * sizeof(f16));     // 24 MB
  float* als  = (float*)nxt((size_t)ROWS * 3 * 4);
  float* ald  = (float*)nxt((size_t)ROWS * 3 * 4);
  float* hcur = (float*)nxt((size_t)ROWS * 64 * 4);                // 16 MB
  float* rowZ = (float*)nxt((size_t)NN * 4);
  float* Zpart= (float*)nxt((size_t)64 * NN * 4);                  // 1 MB
  f16*   SEh  = (f16*)  nxt((size_t)NN * 64 * sizeof(f16));
  f16*   TEh  = (f16*)  nxt((size_t)NN * 64 * sizeof(f16));
  int*   cnt  = (int*)  nxt((size_t)NN * 4);
  int*   curp = (int*)  nxt((size_t)NN * 4);
  int*   offs = (int*)  nxt((size_t)NN * 4);
  int*   esrc = (int*)  nxt((size_t)ETOT * 4);

  dim3 blk(256);
  // CSR build
  k_zero<<<16, blk, 0, stream>>>(cnt, NN);
  k_zero<<<16, blk, 0, stream>>>(curp, NN);
  k_count<<<144, blk, 0, stream>>>(ei, cnt);
  k_scan<<<1, blk, 0, stream>>>(cnt, offs);
  k_fill<<<144, blk, 0, stream>>>(ei, offs, curp, esrc);
  // h0 + HT + adjacency (MFMA path)
  k_seq<<<1024, blk, 0, stream>>>(inp, Wseq, bseq, h);
  k_tr<<<1024, blk, 0, stream>>>(h, HT);
  k_castSE<<<256, blk, 0, stream>>>(SE, SEh);
  k_castTE<<<64, blk, 0, stream>>>(TE, TEh);
  k_adjmm<<<dim3(32, 32), blk, 0, stream>>>(SEh, TEh, Af, Zpart);
  k_rowz<<<16, blk, 0, stream>>>(Zpart, rowZ);
  k_scaleA<<<8192, blk, 0, stream>>>(Af, rowZ);
  // ---- layer 0 ----
  k_gemm<<<dim3(8, 32, 2), blk, 0, stream>>>(Af, HT, adp);
  k_comb0<<<1024, blk, 0, stream>>>(h, adp, Wl[0], bl[0], Wo, bo, h);
  k_tr<<<1024, blk, 0, stream>>>(h, HT);
  // ---- layer 1 ----
  k_xp<3><<<1024, blk, 0, stream>>>(h, Wg[1], xp);
  k_dots<3><<<16384, blk, 0, stream>>>(xp, asrc[1], adst[1], als, ald);
  k_gemm<<<dim3(8, 32, 2), blk, 0, stream>>>(Af, HT, adp);
  k_agg<3><<<16384, blk, 0, stream>>>(xp, als, ald, offs, cnt, esrc, bgp[1], hcur);
  k_comb12<0><<<1024, blk, 0, stream>>>(h, adp, hcur, Wl[1], bl[1], h);
  k_tr<<<1024, blk, 0, stream>>>(h, HT);
  // ---- layer 2 ----
  k_xp<1><<<1024, blk, 0, stream>>>(h, Wg[2], xp);
  k_dots<1><<<16384, blk, 0, stream>>>(xp, asrc[2], adst[2], als, ald);
  k_gemm<<<dim3(8, 32, 2), blk, 0, stream>>>(Af, HT, adp);
  k_agg<1><<<16384, blk, 0, stream>>>(xp, als, ald, offs, cnt, esrc, bgp[2], hcur);
  k_comb12<1><<<1024, blk, 0, stream>>>(h, adp, hcur, Wl[2], bl[2], out);
}

// Round 3
// 512.805 us; speedup vs baseline: 4.8301x; 1.3773x over previous
//
#include <hip/hip_runtime.h>
#include <stdint.h>

// ---- problem constants ----
#define NB 16        // batch
#define NN 4096      // nodes
#define DD 64        // feature dim (== S)
#define EE 32768     // edges (before self loops)
#define ETOT 36864   // edges + self loops
#define ROWS 65536   // B*N

typedef _Float16 f16;
typedef f16   half8 __attribute__((ext_vector_type(8)));
typedef f16   f16x8 __attribute__((ext_vector_type(8)));
typedef float f32x4 __attribute__((ext_vector_type(4)));

__device__ __forceinline__ void gload16(const f16* g, f16* l) {
  __builtin_amdgcn_global_load_lds((const __attribute__((address_space(1))) void*)g,
                                   (__attribute__((address_space(3))) void*)l, 16, 0, 0);
}

// ---------------- CSR build ----------------
__global__ __launch_bounds__(256) void k_zero(int* p, int n) {
  int i = blockIdx.x * 256 + threadIdx.x;
  if (i < n) p[i] = 0;
}

__global__ __launch_bounds__(256) void k_count(const int* __restrict__ ei, int* __restrict__ cnt) {
  int t = blockIdx.x * 256 + threadIdx.x;
  if (t >= ETOT) return;
  int d = (t < EE) ? ei[EE + t] : (t - EE);
  atomicAdd(&cnt[d], 1);
}

__global__ __launch_bounds__(256) void k_scan(const int* __restrict__ cnt, int* __restrict__ offs) {
  __shared__ int part[256];
  int t = threadIdx.x;
  int loc[16]; int s = 0;
  #pragma unroll
  for (int i = 0; i < 16; ++i) { int v = cnt[(t << 4) + i]; loc[i] = s; s += v; }
  part[t] = s;
  __syncthreads();
  int own = s;
  for (int d = 1; d < 256; d <<= 1) {
    int u = (t >= d) ? part[t - d] : 0;
    __syncthreads();
    part[t] += u;
    __syncthreads();
  }
  int base = part[t] - own;
  #pragma unroll
  for (int i = 0; i < 16; ++i) offs[(t << 4) + i] = base + loc[i];
}

__global__ __launch_bounds__(256) void k_fill(const int* __restrict__ ei, const int* __restrict__ offs,
                                              int* __restrict__ cur, int* __restrict__ esrc) {
  int t = blockIdx.x * 256 + threadIdx.x;
  if (t >= ETOT) return;
  int s, d;
  if (t < EE) { s = ei[t]; d = ei[EE + t]; } else { s = d = t - EE; }
  int p = atomicAdd(&cur[d], 1);
  esrc[offs[d] + p] = s;
}

// ---------------- seq_linear: h = in^T @ Wseq + b + in^T ----------------
__global__ __launch_bounds__(256) void k_seq(const float* __restrict__ inp, const float* __restrict__ Wseq,
                                             const float* __restrict__ bseq, float* __restrict__ h) {
  __shared__ float X[64 * 68];
  int t = threadIdx.x;
  int b = blockIdx.x >> 6, n0 = (blockIdx.x & 63) << 6;
  #pragma unroll
  for (int i = 0; i < 16; ++i) {
    int idx = t + (i << 8);
    int s = idx >> 6, nl = idx & 63;
    X[nl * 68 + s] = inp[((size_t)((b << 6) + s) << 12) + n0 + nl];
  }
  __syncthreads();
  int c = t & 63, rg = t >> 6;
  float Wc[64];
  #pragma unroll
  for (int k = 0; k < 64; ++k) Wc[k] = Wseq[(k << 6) + c];
  float bc = bseq[c];
  for (int rr = 0; rr < 16; ++rr) {
    int r = (rg << 4) + rr;
    float a = bc + X[r * 68 + c];
    #pragma unroll
    for (int k4 = 0; k4 < 16; ++k4) {
      float4 x = *(const float4*)&X[r * 68 + (k4 << 2)];
      a = fmaf(x.x, Wc[4*k4+0], a); a = fmaf(x.y, Wc[4*k4+1], a);
      a = fmaf(x.z, Wc[4*k4+2], a); a = fmaf(x.w, Wc[4*k4+3], a);
    }
    h[((size_t)(b << 12) + n0 + r) * 64 + c] = a;
  }
}

// ---------------- transpose h [ (b,n), d ] -> HT f16 [ (b,d), n ] ----------------
__global__ __launch_bounds__(256) void k_tr(const float* __restrict__ h, f16* __restrict__ HT) {
  __shared__ float X[64 * 68];
  int t = threadIdx.x;
  int b = blockIdx.x >> 6, n0 = (blockIdx.x & 63) << 6;
  #pragma unroll
  for (int i = 0; i < 16; ++i) {
    int idx = t + (i << 8);
    int nl = idx >> 6, d = idx & 63;
    X[nl * 68 + d] = h[((size_t)(b << 12) + n0 + nl) * 64 + d];
  }
  __syncthreads();
  int nl = t & 63, dg = t >> 6;
  #pragma unroll
  for (int i = 0; i < 16; ++i) {
    int d = (dg << 4) + i;
    HT[((size_t)((b << 6) + d) << 12) + n0 + nl] = (f16)X[nl * 68 + d];
  }
}

// ---------------- adjacency prep: casts ----------------
__global__ __launch_bounds__(256) void k_castSE(const float* __restrict__ SE, f16* __restrict__ SEh) {
  int i = (blockIdx.x * 256 + threadIdx.x) * 4;
  float4 v = *(const float4*)(SE + i);
  f16 o[4] = {(f16)v.x, (f16)v.y, (f16)v.z, (f16)v.w};
  *(uint64_t*)(SEh + i) = *(uint64_t*)o;
}

__global__ __launch_bounds__(256) void k_castTE(const float* __restrict__ TE, f16* __restrict__ TEh) {
  __shared__ float X[64 * 65];
  int t = threadIdx.x;
  int j0 = blockIdx.x << 6;
  #pragma unroll
  for (int i = 0; i < 16; ++i) {
    int idx = t + (i << 8);           // 0..4095 = 64k x 64j
    int k = idx >> 6, jl = idx & 63;
    X[jl * 65 + k] = TE[((size_t)k << 12) + j0 + jl];
  }
  __syncthreads();
  int jl = t >> 2, kg = t & 3;        // 4 threads per output row, 16 k each
  f16 o[16];
  #pragma unroll
  for (int i = 0; i < 16; ++i) o[i] = (f16)X[jl * 65 + (kg << 4) + i];
  f16* dst = TEh + ((size_t)(j0 + jl) << 6) + (kg << 4);
  *(uint64_t*)(dst + 0) = *(uint64_t*)(o + 0);
  *(uint64_t*)(dst + 4) = *(uint64_t*)(o + 4);
  *(uint64_t*)(dst + 8) = *(uint64_t*)(o + 8);
  *(uint64_t*)(dst + 12) = *(uint64_t*)(o + 12);
}

// ---------------- adjacency MFMA GEMM: A = exp(relu(SEh @ TEh^T)), row partial sums ----------------
__global__ __launch_bounds__(256) void k_adjmm(const f16* __restrict__ SEh, const f16* __restrict__ TEh,
                                               f16* __restrict__ A, float* __restrict__ Zpart) {
  __shared__ f16 Al[128 * 32];
  __shared__ f16 Bl[128 * 32];
  const int t = threadIdx.x, lane = t & 63, w = t >> 6;
  const int m0 = blockIdx.y << 7, j0 = blockIdx.x << 7;
  const int l15 = lane & 15, lhi = lane >> 4;
  const int wm = (w >> 1) << 6, wj = (w & 1) << 6;
  f32x4 acc[4][4] = {};
  const int c0 = (w << 6) + lane;
  const int row0 = c0 >> 2, ko0 = (c0 & 3) << 3;
  const int c1 = c0 + 256;
  const int row1 = c1 >> 2, ko1 = (c1 & 3) << 3;
  const f16* ga0 = SEh + (size_t)(m0 + row0) * 64 + ko0;
  const f16* ga1 = SEh + (size_t)(m0 + row1) * 64 + ko1;
  const f16* gb0 = TEh + (size_t)(j0 + row0) * 64 + ko0;
  const f16* gb1 = TEh + (size_t)(j0 + row1) * 64 + ko1;
  f16* la0 = Al + c0 * 8; f16* la1 = Al + c1 * 8;
  f16* lb0 = Bl + c0 * 8; f16* lb1 = Bl + c1 * 8;
  for (int kt = 0; kt < 2; ++kt) {
    const int kof = kt << 5;
    gload16(ga0 + kof, la0);
    gload16(ga1 + kof, la1);
    gload16(gb0 + kof, lb0);
    gload16(gb1 + kof, lb1);
    __syncthreads();
    half8 af[4], bf[4];
    #pragma unroll
    for (int i = 0; i < 4; ++i) {
      af[i] = *(const half8*)(Al + (wm + i * 16 + l15) * 32 + lhi * 8);
      bf[i] = *(const half8*)(Bl + (wj + i * 16 + l15) * 32 + lhi * 8);
    }
    #pragma unroll
    for (int mi = 0; mi < 4; ++mi)
      #pragma unroll
      for (int nj = 0; nj < 4; ++nj)
        acc[mi][nj] = __builtin_amdgcn_mfma_f32_16x16x32_f16(af[mi], bf[nj], acc[mi][nj], 0, 0, 0);
    __syncthreads();
  }
  // epilogue: e = exp(relu(.)), store f16, accumulate per-row partial sums
  float rs[4][4];
  #pragma unroll
  for (int mi = 0; mi < 4; ++mi)
    #pragma unroll
    for (int r = 0; r < 4; ++r) rs[mi][r] = 0.f;
  #pragma unroll
  for (int mi = 0; mi < 4; ++mi)
    #pragma unroll
    for (int nj = 0; nj < 4; ++nj)
      #pragma unroll
      for (int r = 0; r < 4; ++r) {
        int row = m0 + wm + mi * 16 + lhi * 4 + r;
        int col = j0 + wj + nj * 16 + l15;
        float e = __expf(fmaxf(acc[mi][nj][r], 0.f));
        f16 eh = (f16)e;
        A[((size_t)row << 12) + col] = eh;
        rs[mi][r] += (float)eh;      // sum the rounded value for consistency
      }
  #pragma unroll
  for (int mi = 0; mi < 4; ++mi)
    #pragma unroll
    for (int r = 0; r < 4; ++r) {
      float s = rs[mi][r];
      s += __shfl_xor(s, 1); s += __shfl_xor(s, 2);
      s += __shfl_xor(s, 4); s += __shfl_xor(s, 8);
      rs[mi][r] = s;
    }
  if (l15 == 0) {
    int p = (blockIdx.x << 1) + (w & 1);
    #pragma unroll
    for (int mi = 0; mi < 4; ++mi)
      #pragma unroll
      for (int r = 0; r < 4; ++r)
        Zpart[((size_t)p << 12) + m0 + wm + mi * 16 + lhi * 4 + r] = rs[mi][r];
  }
}

__global__ __launch_bounds__(256) void k_rowz(const float* __restrict__ Zpart, float* __restrict__ rowZ) {
  int row = blockIdx.x * 256 + threadIdx.x;
  float s = 0.f;
  #pragma unroll 8
  for (int p = 0; p < 64; ++p) s += Zpart[((size_t)p << 12) + row];
  rowZ[row] = 1.f / s;
}

__global__ __launch_bounds__(256) void k_scaleA(f16* __restrict__ A, const float* __restrict__ rowZ) {
  size_t base = ((size_t)blockIdx.x * 256 + threadIdx.x) * 8;
  float zi = rowZ[base >> 12];
  f16x8 v = *(const f16x8*)(A + base);
  #pragma unroll
  for (int i = 0; i < 8; ++i) v[i] = (f16)((float)v[i] * zi);
  *(f16x8*)(A + base) = v;
}

// ---------------- big GEMM: C[m, j] = sum_k A[m,k] * BT[j,k]; k-split via blockIdx.z ----------------
__global__ __launch_bounds__(256) void k_gemm(const f16* __restrict__ A, const f16* __restrict__ BT,
                                              float* __restrict__ Cout) {
  __shared__ f16 Al[128 * 32];
  __shared__ f16 Bl[128 * 32];
  const int t = threadIdx.x, lane = t & 63, w = t >> 6;
  const int m0 = blockIdx.y << 7, j0 = blockIdx.x << 7;
  const int kbase = blockIdx.z << 11;
  float* __restrict__ C = Cout + ((size_t)blockIdx.z << 22);
  const int l15 = lane & 15, lhi = lane >> 4;
  const int wm = (w >> 1) << 6, wj = (w & 1) << 6;
  f32x4 acc[4][4] = {};
  const int c0 = (w << 6) + lane;
  const int row0 = c0 >> 2, ko0 = (c0 & 3) << 3;
  const int c1 = c0 + 256;
  const int row1 = c1 >> 2, ko1 = (c1 & 3) << 3;
  const f16* ga0 = A  + (size_t)(m0 + row0) * 4096 + kbase + ko0;
  const f16* ga1 = A  + (size_t)(m0 + row1) * 4096 + kbase + ko1;
  const f16* gb0 = BT + (size_t)(j0 + row0) * 4096 + kbase + ko0;
  const f16* gb1 = BT + (size_t)(j0 + row1) * 4096 + kbase + ko1;
  f16* la0 = Al + c0 * 8; f16* la1 = Al + c1 * 8;
  f16* lb0 = Bl + c0 * 8; f16* lb1 = Bl + c1 * 8;
  for (int kt = 0; kt < 64; ++kt) {
    const int kof = kt << 5;
    gload16(ga0 + kof, la0);
    gload16(ga1 + kof, la1);
    gload16(gb0 + kof, lb0);
    gload16(gb1 + kof, lb1);
    __syncthreads();
    half8 af[4], bf[4];
    #pragma unroll
    for (int i = 0; i < 4; ++i) {
      af[i] = *(const half8*)(Al + (wm + i * 16 + l15) * 32 + lhi * 8);
      bf[i] = *(const half8*)(Bl + (wj + i * 16 + l15) * 32 + lhi * 8);
    }
    #pragma unroll
    for (int mi = 0; mi < 4; ++mi)
      #pragma unroll
      for (int nj = 0; nj < 4; ++nj)
        acc[mi][nj] = __builtin_amdgcn_mfma_f32_16x16x32_f16(af[mi], bf[nj], acc[mi][nj], 0, 0, 0);
    __syncthreads();
  }
  #pragma unroll
  for (int mi = 0; mi < 4; ++mi)
    #pragma unroll
    for (int nj = 0; nj < 4; ++nj)
      #pragma unroll
      for (int r = 0; r < 4; ++r) {
        int row = m0 + wm + mi * 16 + lhi * 4 + r;
        int col = j0 + wj + nj * 16 + l15;
        C[(size_t)row * 1024 + col] = acc[mi][nj][r];
      }
}

// ---------------- xp = h @ Wg  (f16 out) ----------------
template<int H>
__global__ __launch_bounds__(256) void k_xp(const float* __restrict__ h, const float* __restrict__ Wg,
                                            f16* __restrict__ xp) {
  __shared__ float X[64 * 68];
  int t = threadIdx.x;
  size_t r0 = (size_t)blockIdx.x << 6;
  #pragma unroll
  for (int i = 0; i < 16; ++i) {
    int idx = t + (i << 8);
    int nl = idx >> 6, d = idx & 63;
    X[nl * 68 + d] = h[(r0 + nl) * 64 + d];
  }
  __syncthreads();
  int c = t & 63, rg = t >> 6;
  for (int hh = 0; hh < H; ++hh) {
    float Wc[64];
    #pragma unroll
    for (int k = 0; k < 64; ++k) Wc[k] = Wg[k * (H * 64) + (hh << 6) + c];
    for (int rr = 0; rr < 16; ++rr) {
      int r = (rg << 4) + rr;
      float a = 0.f;
      #pragma unroll
      for (int k4 = 0; k4 < 16; ++k4) {
        float4 x = *(const float4*)&X[r * 68 + (k4 << 2)];
        a = fmaf(x.x, Wc[4*k4+0], a); a = fmaf(x.y, Wc[4*k4+1], a);
        a = fmaf(x.z, Wc[4*k4+2], a); a = fmaf(x.w, Wc[4*k4+3], a);
      }
      xp[(r0 + r) * (H * 64) + (hh << 6) + c] = (f16)a;
    }
  }
}

// ---------------- attention dots: als/ald = xp . a_src/a_dst ----------------
template<int H>
__global__ __launch_bounds__(256) void k_dots(const f16* __restrict__ xp, const float* __restrict__ asrc,
                                              const float* __restrict__ adst,
                                              float* __restrict__ als, float* __restrict__ ald) {
  int t = threadIdx.x, lane = t & 63;
  size_t r = ((size_t)blockIdx.x << 2) + (t >> 6);
  const f16* row = xp + r * (H * 64);
  #pragma unroll
  for (int hh = 0; hh < H; ++hh) {
    float v = (float)row[(hh << 6) + lane];
    float a = v * asrc[(hh << 6) + lane];
    float d = v * adst[(hh << 6) + lane];
    #pragma unroll
    for (int s = 32; s; s >>= 1) { a += __shfl_xor(a, s); d += __shfl_xor(d, s); }
    if (lane == 0) { als[r * H + hh] = a; ald[r * H + hh] = d; }
  }
}

// ---------------- GAT aggregation: one wave per (b, node), lane-parallel softmax ----------------
template<int H>
__global__ __launch_bounds__(256) void k_agg(const f16* __restrict__ xp, const float* __restrict__ als,
                                             const float* __restrict__ ald,
                                             const int* __restrict__ offs, const int* __restrict__ cnt,
                                             const int* __restrict__ esrc, const float* __restrict__ bg,
                                             float* __restrict__ hcur) {
  __shared__ float wbuf[4][H * 64];
  __shared__ int   sbuf[4][64];
  int t = threadIdx.x, lane = t & 63, wv = t >> 6;
  int wid = (blockIdx.x << 2) + wv;
  int b = wid >> 12, n = wid & 4095;
  size_t rbase = (size_t)b << 12;
  int o = offs[n], c = cnt[n];
  float aldh[H], m[H], z[H], acc[H];
  #pragma unroll
  for (int hh = 0; hh < H; ++hh) {
    aldh[hh] = ald[(rbase + n) * H + hh];
    m[hh] = -1e30f; z[hh] = 0.f; acc[hh] = 0.f;
  }
  for (int e0 = 0; e0 < c; e0 += 64) {
    int ce = min(64, c - e0);
    // phase 1: lane-parallel ev + weights
    float evl[H]; int sl = 0;
    if (lane < ce) {
      sl = esrc[o + e0 + lane];
      #pragma unroll
      for (int hh = 0; hh < H; ++hh) {
        float ev = als[(rbase + sl) * H + hh] + aldh[hh];
        evl[hh] = ev > 0.f ? ev : 0.2f * ev;
      }
    } else {
      #pragma unroll
      for (int hh = 0; hh < H; ++hh) evl[hh] = -1e30f;
    }
    sbuf[wv][lane] = sl;
    #pragma unroll
    for (int hh = 0; hh < H; ++hh) {
      float v = evl[hh];
      #pragma unroll
      for (int s = 1; s < 64; s <<= 1) v = fmaxf(v, __shfl_xor(v, s));
      float mn = fmaxf(m[hh], v);
      float sc = __expf(m[hh] - mn);               // 0 on first chunk, 1 if max unchanged
      z[hh] *= sc; acc[hh] *= sc; m[hh] = mn;
      float w = (lane < ce) ? __expf(evl[hh] - mn) : 0.f;
      wbuf[wv][hh * 64 + lane] = w;
      float zs = w;
      #pragma unroll
      for (int s = 1; s < 64; s <<= 1) zs += __shfl_xor(zs, s);
      z[hh] += zs;
    }
    // phase 2: d-parallel aggregation, no exp in loop (weights broadcast from LDS)
    for (int e = 0; e < ce; ++e) {
      int s = sbuf[wv][e];
      const f16* row = xp + (rbase + s) * (size_t)(H * 64) + lane;
      #pragma unroll
      for (int hh = 0; hh < H; ++hh)
        acc[hh] = fmaf(wbuf[wv][hh * 64 + e], (float)row[hh << 6], acc[hh]);
    }
  }
  float r = 0.f;
  #pragma unroll
  for (int hh = 0; hh < H; ++hh) r += acc[hh] / z[hh];
  hcur[(rbase + n) * 64 + lane] = r * (1.f / H) + bg[lane];
}

// ---------------- layer-0 combine ----------------
__global__ __launch_bounds__(256) void k_comb0(const float* __restrict__ h, const float* __restrict__ adp,
                                               const float* __restrict__ Wl, const float* __restrict__ bl,
                                               const float* __restrict__ Wo, const float* __restrict__ bo,
                                               float* __restrict__ hout) {
  __shared__ float Xa[64 * 68];
  __shared__ float Xh[64 * 68];
  int t = threadIdx.x;
  int b = blockIdx.x >> 6, n0 = (blockIdx.x & 63) << 6;
  #pragma unroll
  for (int i = 0; i < 16; ++i) {
    int idx = t + (i << 8);
    int nl = idx >> 6, d = idx & 63;
    size_t arow = ((size_t)(n0 + nl) << 10) + (b << 6) + d;
    Xa[nl * 68 + d] = adp[arow] + adp[arow + ((size_t)4096 * 1024)];
    Xh[nl * 68 + d] = h[((size_t)(b << 12) + n0 + nl) * 64 + d];
  }
  __syncthreads();
  int c = t & 63, rg = t >> 6;
  float blc = bl[c], boc = bo[c];
  float Wc[64], gv[16];
  #pragma unroll
  for (int k = 0; k < 64; ++k) Wc[k] = Wl[(k << 6) + c];
  for (int rr = 0; rr < 16; ++rr) {
    int r = (rg << 4) + rr;
    float ag = blc;
    #pragma unroll
    for (int k4 = 0; k4 < 16; ++k4) {
      float4 x = *(const float4*)&Xa[r * 68 + (k4 << 2)];
      ag = fmaf(x.x, Wc[4*k4+0], ag); ag = fmaf(x.y, Wc[4*k4+1], ag);
      ag = fmaf(x.z, Wc[4*k4+2], ag); ag = fmaf(x.w, Wc[4*k4+3], ag);
    }
    gv[rr] = 1.f / (1.f + __expf(-ag));
  }
  #pragma unroll
  for (int k = 0; k < 64; ++k) Wc[k] = Wo[(k << 6) + c];
  for (int rr = 0; rr < 16; ++rr) {
    int r = (rg << 4) + rr;
    float ao = boc;
    #pragma unroll
    for (int k4 = 0; k4 < 16; ++k4) {
      float4 x = *(const float4*)&Xh[r * 68 + (k4 << 2)];
      ao = fmaf(x.x, Wc[4*k4+0], ao); ao = fmaf(x.y, Wc[4*k4+1], ao);
      ao = fmaf(x.z, Wc[4*k4+2], ao); ao = fmaf(x.w, Wc[4*k4+3], ao);
    }
    float hv = Xh[r * 68 + c];
    float g = gv[rr];
    hout[((size_t)(b << 12) + n0 + r) * 64 + c] = tanhf(hv) * g + ao * (1.f - g);
  }
}

// ---------------- layer-1/2 combine ----------------
template<int ACT>   // 0: leaky 0.01, 1: relu
__global__ __launch_bounds__(256) void k_comb12(const float* __restrict__ h, const float* __restrict__ adp,
                                                const float* __restrict__ hcur, const float* __restrict__ Wl,
                                                const float* __restrict__ bl, float* __restrict__ hout) {
  __shared__ float Xa[64 * 68];
  int t = threadIdx.x;
  int b = blockIdx.x >> 6, n0 = (blockIdx.x & 63) << 6;
  #pragma unroll
  for (int i = 0; i < 16; ++i) {
    int idx = t + (i << 8);
    int nl = idx >> 6, d = idx & 63;
    size_t arow = ((size_t)(n0 + nl) << 10) + (b << 6) + d;
    Xa[nl * 68 + d] = adp[arow] + adp[arow + ((size_t)4096 * 1024)];
  }
  __syncthreads();
  int c = t & 63, rg = t >> 6;
  float Wc[64];
  #pragma unroll
  for (int k = 0; k < 64; ++k) Wc[k] = Wl[(k << 6) + c];
  float blc = bl[c];
  for (int rr = 0; rr < 16; ++rr) {
    int r = (rg << 4) + rr;
    float ag = blc;
    #pragma unroll
    for (int k4 = 0; k4 < 16; ++k4) {
      float4 x = *(const float4*)&Xa[r * 68 + (k4 << 2)];
      ag = fmaf(x.x, Wc[4*k4+0], ag); ag = fmaf(x.y, Wc[4*k4+1], ag);
      ag = fmaf(x.z, Wc[4*k4+2], ag); ag = fmaf(x.w, Wc[4*k4+3], ag);
    }
    float g = 1.f / (1.f + __expf(-ag));
    size_t ridx = ((size_t)(b << 12) + n0 + r) * 64 + c;
    float hv = h[ridx], cv = hcur[ridx];
    float act = ACT ? fmaxf(cv, 0.f) : (cv > 0.f ? cv : 0.01f * cv);
    hout[ridx] = act * g + hv * (1.f - g);
  }
}

// ---------------- host launch ----------------
extern "C" void kernel_launch(void* const* d_in, const int* in_sizes, int n_in,
                              void* d_out, int out_size, void* d_ws, size_t ws_size,
                              hipStream_t stream) {
  (void)in_sizes; (void)n_in; (void)out_size; (void)ws_size;
  const float* inp  = (const float*)d_in[0];
  const int*   ei   = (const int*)d_in[1];
  const float* Wseq = (const float*)d_in[2];
  const float* bseq = (const float*)d_in[3];
  const float* SE   = (const float*)d_in[4];
  const float* TE   = (const float*)d_in[5];
  const float* Wg[3]   = {(const float*)d_in[6],  (const float*)d_in[12], (const float*)d_in[18]};
  const float* asrc[3] = {(const float*)d_in[7],  (const float*)d_in[13], (const float*)d_in[19]};
  const float* adst[3] = {(const float*)d_in[8],  (const float*)d_in[14], (const float*)d_in[20]};
  const float* bgp[3]  = {(const float*)d_in[9],  (const float*)d_in[15], (const float*)d_in[21]};
  const float* Wl[3]   = {(const float*)d_in[10], (const float*)d_in[16], (const float*)d_in[22]};
  const float* bl[3]   = {(const float*)d_in[11], (const float*)d_in[17], (const float*)d_in[23]};
  const float* Wo = (const float*)d_in[24];
  const float* bo = (const float*)d_in[25];
  float* out = (float*)d_out;

  uint8_t* ws = (uint8_t*)d_ws;
  size_t o = 0;
  auto nxt = [&](size_t sz) { void* p = ws + o; o += (sz + 255) & ~(size_t)255; return p; };
  f16*   Af   = (f16*)  nxt((size_t)NN * NN * sizeof(f16));        // 32 MB
  f16*   HT   = (f16*)  nxt((size_t)1024 * NN * sizeof(f16));      // 8 MB
  float* h    = (float*)nxt((size_t)ROWS * 64 * 4);                // 16 MB
  float* adp  = (float*)nxt((size_t)2 * NN * 1024 * 4);            // 32 MB (2 k-split parts)
  f16*   xp   = (f16*)  nxt((size_t)ROWS * 192 * sizeof(f16));     // 24 MB
  float* als  = (float*)nxt((size_t)ROWS * 3 * 4);
  float* ald  = (float*)nxt((size_t)ROWS * 3 * 4);
  float* hcur = (float*)nxt((size_t)ROWS * 64 * 4);                // 16 MB
  float* rowZ = (float*)nxt((size_t)NN * 4);
  float* Zpart= (float*)nxt((size_t)64 * NN * 4);                  // 1 MB
  f16*   SEh  = (f16*)  nxt((size_t)NN * 64 * sizeof(f16));
  f16*   TEh  = (f16*)  nxt((size_t)NN * 64 * sizeof(f16));
  int*   cnt  = (int*)  nxt((size_t)NN * 4);
  int*   curp = (int*)  nxt((size_t)NN * 4);
  int*   offs = (int*)  nxt((size_t)NN * 4);
  int*   esrc = (int*)  nxt((size_t)ETOT * 4);

  dim3 blk(256);
  // CSR build
  k_zero<<<16, blk, 0, stream>>>(cnt, NN);
  k_zero<<<16, blk, 0, stream>>>(curp, NN);
  k_count<<<144, blk, 0, stream>>>(ei, cnt);
  k_scan<<<1, blk, 0, stream>>>(cnt, offs);
  k_fill<<<144, blk, 0, stream>>>(ei, offs, curp, esrc);
  // h0 + HT + adjacency (MFMA path)
  k_seq<<<1024, blk, 0, stream>>>(inp, Wseq, bseq, h);
  k_tr<<<1024, blk, 0, stream>>>(h, HT);
  k_castSE<<<256, blk, 0, stream>>>(SE, SEh);
  k_castTE<<<64, blk, 0, stream>>>(TE, TEh);
  k_adjmm<<<dim3(32, 32), blk, 0, stream>>>(SEh, TEh, Af, Zpart);
  k_rowz<<<16, blk, 0, stream>>>(Zpart, rowZ);
  k_scaleA<<<8192, blk, 0, stream>>>(Af, rowZ);
  // ---- layer 0 ----
  k_gemm<<<dim3(8, 32, 2), blk, 0, stream>>>(Af, HT, adp);
  k_comb0<<<1024, blk, 0, stream>>>(h, adp, Wl[0], bl[0], Wo, bo, h);
  k_tr<<<1024, blk, 0, stream>>>(h, HT);
  // ---- layer 1 ----
  k_xp<3><<<1024, blk, 0, stream>>>(h, Wg[1], xp);
  k_dots<3><<<16384, blk, 0, stream>>>(xp, asrc[1], adst[1], als, ald);
  k_gemm<<<dim3(8, 32, 2), blk, 0, stream>>>(Af, HT, adp);
  k_agg<3><<<16384, blk, 0, stream>>>(xp, als, ald, offs, cnt, esrc, bgp[1], hcur);
  k_comb12<0><<<1024, blk, 0, stream>>>(h, adp, hcur, Wl[1], bl[1], h);
  k_tr<<<1024, blk, 0, stream>>>(h, HT);
  // ---- layer 2 ----
  k_xp<1><<<1024, blk, 0, stream>>>(h, Wg[2], xp);
  k_dots<1><<<16384, blk, 0, stream>>>(xp, asrc[2], adst[2], als, ald);
  k_gemm<<<dim3(8, 32, 2), blk, 0, stream>>>(Af, HT, adp);
  k_agg<1><<<16384, blk, 0, stream>>>(xp, als, ald, offs, cnt, esrc, bgp[2], hcur);
  k_comb12<1><<<1024, blk, 0, stream>>>(h, adp, hcur, Wl[2], bl[2], out);
}

// Round 4
// 500.731 us; speedup vs baseline: 4.9466x; 1.0241x over previous
//
#include <hip/hip_runtime.h>
#include <stdint.h>

// ---- problem constants ----
#define NB 16        // batch
#define NN 4096      // nodes
#define DD 64        // feature dim (== S)
#define EE 32768     // edges (before self loops)
#define ETOT 36864   // edges + self loops
#define ROWS 65536   // B*N
#define KSPLIT 4

typedef _Float16 f16;
typedef f16   half8 __attribute__((ext_vector_type(8)));
typedef f16   f16x8 __attribute__((ext_vector_type(8)));
typedef float f32x4 __attribute__((ext_vector_type(4)));

__device__ __forceinline__ void gload16(const f16* g, f16* l) {
  __builtin_amdgcn_global_load_lds((const __attribute__((address_space(1))) void*)g,
                                   (__attribute__((address_space(3))) void*)l, 16, 0, 0);
}

// ---------------- CSR build ----------------
__global__ __launch_bounds__(256) void k_zero(int* p, int n) {
  int i = blockIdx.x * 256 + threadIdx.x;
  if (i < n) p[i] = 0;
}

__global__ __launch_bounds__(256) void k_count(const int* __restrict__ ei, int* __restrict__ cnt) {
  int t = blockIdx.x * 256 + threadIdx.x;
  if (t >= ETOT) return;
  int d = (t < EE) ? ei[EE + t] : (t - EE);
  atomicAdd(&cnt[d], 1);
}

__global__ __launch_bounds__(256) void k_scan(const int* __restrict__ cnt, int* __restrict__ offs) {
  __shared__ int part[256];
  int t = threadIdx.x;
  int loc[16]; int s = 0;
  #pragma unroll
  for (int i = 0; i < 16; ++i) { int v = cnt[(t << 4) + i]; loc[i] = s; s += v; }
  part[t] = s;
  __syncthreads();
  int own = s;
  for (int d = 1; d < 256; d <<= 1) {
    int u = (t >= d) ? part[t - d] : 0;
    __syncthreads();
    part[t] += u;
    __syncthreads();
  }
  int base = part[t] - own;
  #pragma unroll
  for (int i = 0; i < 16; ++i) offs[(t << 4) + i] = base + loc[i];
}

__global__ __launch_bounds__(256) void k_fill(const int* __restrict__ ei, const int* __restrict__ offs,
                                              int* __restrict__ cur, int* __restrict__ esrc) {
  int t = blockIdx.x * 256 + threadIdx.x;
  if (t >= ETOT) return;
  int s, d;
  if (t < EE) { s = ei[t]; d = ei[EE + t]; } else { s = d = t - EE; }
  int p = atomicAdd(&cur[d], 1);
  esrc[offs[d] + p] = s;
}

// ---------------- seq_linear: h = in^T @ Wseq + b + in^T ----------------
__global__ __launch_bounds__(256) void k_seq(const float* __restrict__ inp, const float* __restrict__ Wseq,
                                             const float* __restrict__ bseq, float* __restrict__ h) {
  __shared__ float X[64 * 68];
  int t = threadIdx.x;
  int b = blockIdx.x >> 6, n0 = (blockIdx.x & 63) << 6;
  #pragma unroll
  for (int i = 0; i < 16; ++i) {
    int idx = t + (i << 8);
    int s = idx >> 6, nl = idx & 63;
    X[nl * 68 + s] = inp[((size_t)((b << 6) + s) << 12) + n0 + nl];
  }
  __syncthreads();
  int c = t & 63, rg = t >> 6;
  float Wc[64];
  #pragma unroll
  for (int k = 0; k < 64; ++k) Wc[k] = Wseq[(k << 6) + c];
  float bc = bseq[c];
  for (int rr = 0; rr < 16; ++rr) {
    int r = (rg << 4) + rr;
    float a = bc + X[r * 68 + c];
    #pragma unroll
    for (int k4 = 0; k4 < 16; ++k4) {
      float4 x = *(const float4*)&X[r * 68 + (k4 << 2)];
      a = fmaf(x.x, Wc[4*k4+0], a); a = fmaf(x.y, Wc[4*k4+1], a);
      a = fmaf(x.z, Wc[4*k4+2], a); a = fmaf(x.w, Wc[4*k4+3], a);
    }
    h[((size_t)(b << 12) + n0 + r) * 64 + c] = a;
  }
}

// ---------------- transpose h [ (b,n), d ] -> HT f16 [ (b,d), n ] ----------------
__global__ __launch_bounds__(256) void k_tr(const float* __restrict__ h, f16* __restrict__ HT) {
  __shared__ float X[64 * 68];
  int t = threadIdx.x;
  int b = blockIdx.x >> 6, n0 = (blockIdx.x & 63) << 6;
  #pragma unroll
  for (int i = 0; i < 16; ++i) {
    int idx = t + (i << 8);
    int nl = idx >> 6, d = idx & 63;
    X[nl * 68 + d] = h[((size_t)(b << 12) + n0 + nl) * 64 + d];
  }
  __syncthreads();
  int nl = t & 63, dg = t >> 6;
  #pragma unroll
  for (int i = 0; i < 16; ++i) {
    int d = (dg << 4) + i;
    HT[((size_t)((b << 6) + d) << 12) + n0 + nl] = (f16)X[nl * 68 + d];
  }
}

// ---------------- adjacency prep: casts ----------------
__global__ __launch_bounds__(256) void k_castSE(const float* __restrict__ SE, f16* __restrict__ SEh) {
  int i = (blockIdx.x * 256 + threadIdx.x) * 4;
  float4 v = *(const float4*)(SE + i);
  f16 o[4] = {(f16)v.x, (f16)v.y, (f16)v.z, (f16)v.w};
  *(uint64_t*)(SEh + i) = *(uint64_t*)o;
}

__global__ __launch_bounds__(256) void k_castTE(const float* __restrict__ TE, f16* __restrict__ TEh) {
  __shared__ float X[64 * 65];
  int t = threadIdx.x;
  int j0 = blockIdx.x << 6;
  #pragma unroll
  for (int i = 0; i < 16; ++i) {
    int idx = t + (i << 8);           // 0..4095 = 64k x 64j
    int k = idx >> 6, jl = idx & 63;
    X[jl * 65 + k] = TE[((size_t)k << 12) + j0 + jl];
  }
  __syncthreads();
  int jl = t >> 2, kg = t & 3;        // 4 threads per output row, 16 k each
  f16 o[16];
  #pragma unroll
  for (int i = 0; i < 16; ++i) o[i] = (f16)X[jl * 65 + (kg << 4) + i];
  f16* dst = TEh + ((size_t)(j0 + jl) << 6) + (kg << 4);
  *(uint64_t*)(dst + 0) = *(uint64_t*)(o + 0);
  *(uint64_t*)(dst + 4) = *(uint64_t*)(o + 4);
  *(uint64_t*)(dst + 8) = *(uint64_t*)(o + 8);
  *(uint64_t*)(dst + 12) = *(uint64_t*)(o + 12);
}

// ---------------- adjacency MFMA GEMM: A = exp(relu(SEh @ TEh^T)), row partial sums ----------------
__global__ __launch_bounds__(256) void k_adjmm(const f16* __restrict__ SEh, const f16* __restrict__ TEh,
                                               f16* __restrict__ A, float* __restrict__ Zpart) {
  __shared__ f16 Al[128 * 32];
  __shared__ f16 Bl[128 * 32];
  const int t = threadIdx.x, lane = t & 63, w = t >> 6;
  const int m0 = blockIdx.y << 7, j0 = blockIdx.x << 7;
  const int l15 = lane & 15, lhi = lane >> 4;
  const int wm = (w >> 1) << 6, wj = (w & 1) << 6;
  f32x4 acc[4][4] = {};
  const int c0 = (w << 6) + lane;
  const int row0 = c0 >> 2, ko0 = (c0 & 3) << 3;
  const int c1 = c0 + 256;
  const int row1 = c1 >> 2, ko1 = (c1 & 3) << 3;
  const f16* ga0 = SEh + (size_t)(m0 + row0) * 64 + ko0;
  const f16* ga1 = SEh + (size_t)(m0 + row1) * 64 + ko1;
  const f16* gb0 = TEh + (size_t)(j0 + row0) * 64 + ko0;
  const f16* gb1 = TEh + (size_t)(j0 + row1) * 64 + ko1;
  f16* la0 = Al + c0 * 8; f16* la1 = Al + c1 * 8;
  f16* lb0 = Bl + c0 * 8; f16* lb1 = Bl + c1 * 8;
  for (int kt = 0; kt < 2; ++kt) {
    const int kof = kt << 5;
    gload16(ga0 + kof, la0);
    gload16(ga1 + kof, la1);
    gload16(gb0 + kof, lb0);
    gload16(gb1 + kof, lb1);
    __syncthreads();
    half8 af[4], bf[4];
    #pragma unroll
    for (int i = 0; i < 4; ++i) {
      af[i] = *(const half8*)(Al + (wm + i * 16 + l15) * 32 + lhi * 8);
      bf[i] = *(const half8*)(Bl + (wj + i * 16 + l15) * 32 + lhi * 8);
    }
    #pragma unroll
    for (int mi = 0; mi < 4; ++mi)
      #pragma unroll
      for (int nj = 0; nj < 4; ++nj)
        acc[mi][nj] = __builtin_amdgcn_mfma_f32_16x16x32_f16(af[mi], bf[nj], acc[mi][nj], 0, 0, 0);
    __syncthreads();
  }
  // epilogue: e = exp(relu(.)), store f16, accumulate per-row partial sums
  float rs[4][4];
  #pragma unroll
  for (int mi = 0; mi < 4; ++mi)
    #pragma unroll
    for (int r = 0; r < 4; ++r) rs[mi][r] = 0.f;
  #pragma unroll
  for (int mi = 0; mi < 4; ++mi)
    #pragma unroll
    for (int nj = 0; nj < 4; ++nj)
      #pragma unroll
      for (int r = 0; r < 4; ++r) {
        int row = m0 + wm + mi * 16 + lhi * 4 + r;
        int col = j0 + wj + nj * 16 + l15;
        float e = __expf(fmaxf(acc[mi][nj][r], 0.f));
        f16 eh = (f16)e;
        A[((size_t)row << 12) + col] = eh;
        rs[mi][r] += (float)eh;      // sum the rounded value for consistency
      }
  #pragma unroll
  for (int mi = 0; mi < 4; ++mi)
    #pragma unroll
    for (int r = 0; r < 4; ++r) {
      float s = rs[mi][r];
      s += __shfl_xor(s, 1); s += __shfl_xor(s, 2);
      s += __shfl_xor(s, 4); s += __shfl_xor(s, 8);
      rs[mi][r] = s;
    }
  if (l15 == 0) {
    int p = (blockIdx.x << 1) + (w & 1);
    #pragma unroll
    for (int mi = 0; mi < 4; ++mi)
      #pragma unroll
      for (int r = 0; r < 4; ++r)
        Zpart[((size_t)p << 12) + m0 + wm + mi * 16 + lhi * 4 + r] = rs[mi][r];
  }
}

__global__ __launch_bounds__(256) void k_rowz(const float* __restrict__ Zpart, float* __restrict__ rowZ) {
  int row = blockIdx.x * 256 + threadIdx.x;
  float s = 0.f;
  #pragma unroll 8
  for (int p = 0; p < 64; ++p) s += Zpart[((size_t)p << 12) + row];
  rowZ[row] = 1.f / s;
}

__global__ __launch_bounds__(256) void k_scaleA(f16* __restrict__ A, const float* __restrict__ rowZ) {
  size_t base = ((size_t)blockIdx.x * 256 + threadIdx.x) * 8;
  float zi = rowZ[base >> 12];
  f16x8 v = *(const f16x8*)(A + base);
  #pragma unroll
  for (int i = 0; i < 8; ++i) v[i] = (f16)((float)v[i] * zi);
  *(f16x8*)(A + base) = v;
}

// ---------------- big GEMM: C[m, j] = sum_k A[m,k] * BT[j,k] ----------------
// 2-phase double-buffered prefetch, K-split 4, XCD-aware bijective swizzle.
// grid = 1024 blocks (1D). Block nid decomposition: z = nid>>8 (K-split part),
// m-block = (nid>>3)&31, j-block = nid&7.
__global__ __launch_bounds__(256) void k_gemm(const f16* __restrict__ A, const f16* __restrict__ BT,
                                              float* __restrict__ Cout) {
  __shared__ f16 Al[2][128 * 32];
  __shared__ f16 Bl[2][128 * 32];
  const int t = threadIdx.x, lane = t & 63, w = t >> 6;
  // XCD swizzle: 1024 wgs, 8 XCDs, 128 contiguous per XCD
  const int wgid = blockIdx.x;
  const int nid = (wgid & 7) * 128 + (wgid >> 3);
  const int z = nid >> 8, rem = nid & 255;
  const int m0 = ((rem >> 3) & 31) << 7, j0 = (rem & 7) << 7;
  const int kbase = z << 10;                       // 1024 K per block
  float* __restrict__ C = Cout + ((size_t)z << 22);
  const int l15 = lane & 15, lhi = lane >> 4;
  const int wm = (w >> 1) << 6, wj = (w & 1) << 6;
  f32x4 acc[4][4] = {};
  const int c0 = (w << 6) + lane;
  const int row0 = c0 >> 2, ko0 = (c0 & 3) << 3;
  const int c1 = c0 + 256;
  const int row1 = c1 >> 2, ko1 = (c1 & 3) << 3;
  const f16* ga0 = A  + (size_t)(m0 + row0) * 4096 + kbase + ko0;
  const f16* ga1 = A  + (size_t)(m0 + row1) * 4096 + kbase + ko1;
  const f16* gb0 = BT + (size_t)(j0 + row0) * 4096 + kbase + ko0;
  const f16* gb1 = BT + (size_t)(j0 + row1) * 4096 + kbase + ko1;

  #define STAGE(buf, kt) do {                         \
    const int kof_ = (kt) << 5;                       \
    gload16(ga0 + kof_, Al[buf] + c0 * 8);            \
    gload16(ga1 + kof_, Al[buf] + c1 * 8);            \
    gload16(gb0 + kof_, Bl[buf] + c0 * 8);            \
    gload16(gb1 + kof_, Bl[buf] + c1 * 8);            \
  } while (0)

  STAGE(0, 0);
  __syncthreads();                 // drain prologue stage
  const int NKT = 32;              // 1024 / 32
  for (int kt = 0; kt < NKT; ++kt) {
    const int cur = kt & 1;
    if (kt + 1 < NKT) STAGE(cur ^ 1, kt + 1);   // prefetch next tile (overlaps with compute)
    half8 af[4], bf[4];
    #pragma unroll
    for (int i = 0; i < 4; ++i) {
      af[i] = *(const half8*)(Al[cur] + (wm + i * 16 + l15) * 32 + lhi * 8);
      bf[i] = *(const half8*)(Bl[cur] + (wj + i * 16 + l15) * 32 + lhi * 8);
    }
    #pragma unroll
    for (int mi = 0; mi < 4; ++mi)
      #pragma unroll
      for (int nj = 0; nj < 4; ++nj)
        acc[mi][nj] = __builtin_amdgcn_mfma_f32_16x16x32_f16(af[mi], bf[nj], acc[mi][nj], 0, 0, 0);
    __syncthreads();               // single barrier/K-step: drains vmcnt (next buf ready) + protects cur buf
  }
  #undef STAGE
  #pragma unroll
  for (int mi = 0; mi < 4; ++mi)
    #pragma unroll
    for (int nj = 0; nj < 4; ++nj)
      #pragma unroll
      for (int r = 0; r < 4; ++r) {
        int row = m0 + wm + mi * 16 + lhi * 4 + r;
        int col = j0 + wj + nj * 16 + l15;
        C[(size_t)row * 1024 + col] = acc[mi][nj][r];
      }
}

// ---------------- xp = h @ Wg  (f16 out) ----------------
template<int H>
__global__ __launch_bounds__(256) void k_xp(const float* __restrict__ h, const float* __restrict__ Wg,
                                            f16* __restrict__ xp) {
  __shared__ float X[64 * 68];
  int t = threadIdx.x;
  size_t r0 = (size_t)blockIdx.x << 6;
  #pragma unroll
  for (int i = 0; i < 16; ++i) {
    int idx = t + (i << 8);
    int nl = idx >> 6, d = idx & 63;
    X[nl * 68 + d] = h[(r0 + nl) * 64 + d];
  }
  __syncthreads();
  int c = t & 63, rg = t >> 6;
  for (int hh = 0; hh < H; ++hh) {
    float Wc[64];
    #pragma unroll
    for (int k = 0; k < 64; ++k) Wc[k] = Wg[k * (H * 64) + (hh << 6) + c];
    for (int rr = 0; rr < 16; ++rr) {
      int r = (rg << 4) + rr;
      float a = 0.f;
      #pragma unroll
      for (int k4 = 0; k4 < 16; ++k4) {
        float4 x = *(const float4*)&X[r * 68 + (k4 << 2)];
        a = fmaf(x.x, Wc[4*k4+0], a); a = fmaf(x.y, Wc[4*k4+1], a);
        a = fmaf(x.z, Wc[4*k4+2], a); a = fmaf(x.w, Wc[4*k4+3], a);
      }
      xp[(r0 + r) * (H * 64) + (hh << 6) + c] = (f16)a;
    }
  }
}

// ---------------- attention dots: als/ald = xp . a_src/a_dst ----------------
template<int H>
__global__ __launch_bounds__(256) void k_dots(const f16* __restrict__ xp, const float* __restrict__ asrc,
                                              const float* __restrict__ adst,
                                              float* __restrict__ als, float* __restrict__ ald) {
  int t = threadIdx.x, lane = t & 63;
  size_t r = ((size_t)blockIdx.x << 2) + (t >> 6);
  const f16* row = xp + r * (H * 64);
  #pragma unroll
  for (int hh = 0; hh < H; ++hh) {
    float v = (float)row[(hh << 6) + lane];
    float a = v * asrc[(hh << 6) + lane];
    float d = v * adst[(hh << 6) + lane];
    #pragma unroll
    for (int s = 32; s; s >>= 1) { a += __shfl_xor(a, s); d += __shfl_xor(d, s); }
    if (lane == 0) { als[r * H + hh] = a; ald[r * H + hh] = d; }
  }
}

// ---------------- GAT aggregation: one wave per (b, node), lane-parallel softmax ----------------
template<int H>
__global__ __launch_bounds__(256) void k_agg(const f16* __restrict__ xp, const float* __restrict__ als,
                                             const float* __restrict__ ald,
                                             const int* __restrict__ offs, const int* __restrict__ cnt,
                                             const int* __restrict__ esrc, const float* __restrict__ bg,
                                             float* __restrict__ hcur) {
  __shared__ float wbuf[4][H * 64];
  __shared__ int   sbuf[4][64];
  int t = threadIdx.x, lane = t & 63, wv = t >> 6;
  int wid = (blockIdx.x << 2) + wv;
  int b = wid >> 12, n = wid & 4095;
  size_t rbase = (size_t)b << 12;
  int o = offs[n], c = cnt[n];
  float aldh[H], m[H], z[H], acc[H];
  #pragma unroll
  for (int hh = 0; hh < H; ++hh) {
    aldh[hh] = ald[(rbase + n) * H + hh];
    m[hh] = -1e30f; z[hh] = 0.f; acc[hh] = 0.f;
  }
  for (int e0 = 0; e0 < c; e0 += 64) {
    int ce = min(64, c - e0);
    // phase 1: lane-parallel ev + weights
    float evl[H]; int sl = 0;
    if (lane < ce) {
      sl = esrc[o + e0 + lane];
      #pragma unroll
      for (int hh = 0; hh < H; ++hh) {
        float ev = als[(rbase + sl) * H + hh] + aldh[hh];
        evl[hh] = ev > 0.f ? ev : 0.2f * ev;
      }
    } else {
      #pragma unroll
      for (int hh = 0; hh < H; ++hh) evl[hh] = -1e30f;
    }
    sbuf[wv][lane] = sl;
    #pragma unroll
    for (int hh = 0; hh < H; ++hh) {
      float v = evl[hh];
      #pragma unroll
      for (int s = 1; s < 64; s <<= 1) v = fmaxf(v, __shfl_xor(v, s));
      float mn = fmaxf(m[hh], v);
      float sc = __expf(m[hh] - mn);               // 0 on first chunk, 1 if max unchanged
      z[hh] *= sc; acc[hh] *= sc; m[hh] = mn;
      float w = (lane < ce) ? __expf(evl[hh] - mn) : 0.f;
      wbuf[wv][hh * 64 + lane] = w;
      float zs = w;
      #pragma unroll
      for (int s = 1; s < 64; s <<= 1) zs += __shfl_xor(zs, s);
      z[hh] += zs;
    }
    // phase 2: d-parallel aggregation, no exp in loop (weights broadcast from LDS)
    for (int e = 0; e < ce; ++e) {
      int s = sbuf[wv][e];
      const f16* row = xp + (rbase + s) * (size_t)(H * 64) + lane;
      #pragma unroll
      for (int hh = 0; hh < H; ++hh)
        acc[hh] = fmaf(wbuf[wv][hh * 64 + e], (float)row[hh << 6], acc[hh]);
    }
  }
  float r = 0.f;
  #pragma unroll
  for (int hh = 0; hh < H; ++hh) r += acc[hh] / z[hh];
  hcur[(rbase + n) * 64 + lane] = r * (1.f / H) + bg[lane];
}

// ---------------- layer-0 combine ----------------
__global__ __launch_bounds__(256) void k_comb0(const float* __restrict__ h, const float* __restrict__ adp,
                                               const float* __restrict__ Wl, const float* __restrict__ bl,
                                               const float* __restrict__ Wo, const float* __restrict__ bo,
                                               float* __restrict__ hout) {
  __shared__ float Xa[64 * 68];
  __shared__ float Xh[64 * 68];
  int t = threadIdx.x;
  int b = blockIdx.x >> 6, n0 = (blockIdx.x & 63) << 6;
  #pragma unroll
  for (int i = 0; i < 16; ++i) {
    int idx = t + (i << 8);
    int nl = idx >> 6, d = idx & 63;
    size_t arow = ((size_t)(n0 + nl) << 10) + (b << 6) + d;
    float s = 0.f;
    #pragma unroll
    for (int p = 0; p < KSPLIT; ++p) s += adp[arow + (size_t)p * (4096 * 1024)];
    Xa[nl * 68 + d] = s;
    Xh[nl * 68 + d] = h[((size_t)(b << 12) + n0 + nl) * 64 + d];
  }
  __syncthreads();
  int c = t & 63, rg = t >> 6;
  float blc = bl[c], boc = bo[c];
  float Wc[64], gv[16];
  #pragma unroll
  for (int k = 0; k < 64; ++k) Wc[k] = Wl[(k << 6) + c];
  for (int rr = 0; rr < 16; ++rr) {
    int r = (rg << 4) + rr;
    float ag = blc;
    #pragma unroll
    for (int k4 = 0; k4 < 16; ++k4) {
      float4 x = *(const float4*)&Xa[r * 68 + (k4 << 2)];
      ag = fmaf(x.x, Wc[4*k4+0], ag); ag = fmaf(x.y, Wc[4*k4+1], ag);
      ag = fmaf(x.z, Wc[4*k4+2], ag); ag = fmaf(x.w, Wc[4*k4+3], ag);
    }
    gv[rr] = 1.f / (1.f + __expf(-ag));
  }
  #pragma unroll
  for (int k = 0; k < 64; ++k) Wc[k] = Wo[(k << 6) + c];
  for (int rr = 0; rr < 16; ++rr) {
    int r = (rg << 4) + rr;
    float ao = boc;
    #pragma unroll
    for (int k4 = 0; k4 < 16; ++k4) {
      float4 x = *(const float4*)&Xh[r * 68 + (k4 << 2)];
      ao = fmaf(x.x, Wc[4*k4+0], ao); ao = fmaf(x.y, Wc[4*k4+1], ao);
      ao = fmaf(x.z, Wc[4*k4+2], ao); ao = fmaf(x.w, Wc[4*k4+3], ao);
    }
    float hv = Xh[r * 68 + c];
    float g = gv[rr];
    hout[((size_t)(b << 12) + n0 + r) * 64 + c] = tanhf(hv) * g + ao * (1.f - g);
  }
}

// ---------------- layer-1/2 combine ----------------
template<int ACT>   // 0: leaky 0.01, 1: relu
__global__ __launch_bounds__(256) void k_comb12(const float* __restrict__ h, const float* __restrict__ adp,
                                                const float* __restrict__ hcur, const float* __restrict__ Wl,
                                                const float* __restrict__ bl, float* __restrict__ hout) {
  __shared__ float Xa[64 * 68];
  int t = threadIdx.x;
  int b = blockIdx.x >> 6, n0 = (blockIdx.x & 63) << 6;
  #pragma unroll
  for (int i = 0; i < 16; ++i) {
    int idx = t + (i << 8);
    int nl = idx >> 6, d = idx & 63;
    size_t arow = ((size_t)(n0 + nl) << 10) + (b << 6) + d;
    float s = 0.f;
    #pragma unroll
    for (int p = 0; p < KSPLIT; ++p) s += adp[arow + (size_t)p * (4096 * 1024)];
    Xa[nl * 68 + d] = s;
  }
  __syncthreads();
  int c = t & 63, rg = t >> 6;
  float Wc[64];
  #pragma unroll
  for (int k = 0; k < 64; ++k) Wc[k] = Wl[(k << 6) + c];
  float blc = bl[c];
  for (int rr = 0; rr < 16; ++rr) {
    int r = (rg << 4) + rr;
    float ag = blc;
    #pragma unroll
    for (int k4 = 0; k4 < 16; ++k4) {
      float4 x = *(const float4*)&Xa[r * 68 + (k4 << 2)];
      ag = fmaf(x.x, Wc[4*k4+0], ag); ag = fmaf(x.y, Wc[4*k4+1], ag);
      ag = fmaf(x.z, Wc[4*k4+2], ag); ag = fmaf(x.w, Wc[4*k4+3], ag);
    }
    float g = 1.f / (1.f + __expf(-ag));
    size_t ridx = ((size_t)(b << 12) + n0 + r) * 64 + c;
    float hv = h[ridx], cv = hcur[ridx];
    float act = ACT ? fmaxf(cv, 0.f) : (cv > 0.f ? cv : 0.01f * cv);
    hout[ridx] = act * g + hv * (1.f - g);
  }
}

// ---------------- host launch ----------------
extern "C" void kernel_launch(void* const* d_in, const int* in_sizes, int n_in,
                              void* d_out, int out_size, void* d_ws, size_t ws_size,
                              hipStream_t stream) {
  (void)in_sizes; (void)n_in; (void)out_size; (void)ws_size;
  const float* inp  = (const float*)d_in[0];
  const int*   ei   = (const int*)d_in[1];
  const float* Wseq = (const float*)d_in[2];
  const float* bseq = (const float*)d_in[3];
  const float* SE   = (const float*)d_in[4];
  const float* TE   = (const float*)d_in[5];
  const float* Wg[3]   = {(const float*)d_in[6],  (const float*)d_in[12], (const float*)d_in[18]};
  const float* asrc[3] = {(const float*)d_in[7],  (const float*)d_in[13], (const float*)d_in[19]};
  const float* adst[3] = {(const float*)d_in[8],  (const float*)d_in[14], (const float*)d_in[20]};
  const float* bgp[3]  = {(const float*)d_in[9],  (const float*)d_in[15], (const float*)d_in[21]};
  const float* Wl[3]   = {(const float*)d_in[10], (const float*)d_in[16], (const float*)d_in[22]};
  const float* bl[3]   = {(const float*)d_in[11], (const float*)d_in[17], (const float*)d_in[23]};
  const float* Wo = (const float*)d_in[24];
  const float* bo = (const float*)d_in[25];
  float* out = (float*)d_out;

  uint8_t* ws = (uint8_t*)d_ws;
  size_t o = 0;
  auto nxt = [&](size_t sz) { void* p = ws + o; o += (sz + 255) & ~(size_t)255; return p; };
  f16*   Af   = (f16*)  nxt((size_t)NN * NN * sizeof(f16));        // 32 MB
  f16*   HT   = (f16*)  nxt((size_t)1024 * NN * sizeof(f16));      // 8 MB
  float* h    = (float*)nxt((size_t)ROWS * 64 * 4);                // 16 MB
  float* adp  = (float*)nxt((size_t)KSPLIT * NN * 1024 * 4);       // 64 MB (4 k-split parts)
  f16*   xp   = (f16*)  nxt((size_t)ROWS * 192 * sizeof(f16));     // 24 MB
  float* als  = (float*)nxt((size_t)ROWS * 3 * 4);
  float* ald  = (float*)nxt((size_t)ROWS * 3 * 4);
  float* hcur = (float*)nxt((size_t)ROWS * 64 * 4);                // 16 MB
  float* rowZ = (float*)nxt((size_t)NN * 4);
  float* Zpart= (float*)nxt((size_t)64 * NN * 4);                  // 1 MB
  f16*   SEh  = (f16*)  nxt((size_t)NN * 64 * sizeof(f16));
  f16*   TEh  = (f16*)  nxt((size_t)NN * 64 * sizeof(f16));
  int*   cnt  = (int*)  nxt((size_t)NN * 4);
  int*   curp = (int*)  nxt((size_t)NN * 4);
  int*   offs = (int*)  nxt((size_t)NN * 4);
  int*   esrc = (int*)  nxt((size_t)ETOT * 4);

  dim3 blk(256);
  // CSR build
  k_zero<<<16, blk, 0, stream>>>(cnt, NN);
  k_zero<<<16, blk, 0, stream>>>(curp, NN);
  k_count<<<144, blk, 0, stream>>>(ei, cnt);
  k_scan<<<1, blk, 0, stream>>>(cnt, offs);
  k_fill<<<144, blk, 0, stream>>>(ei, offs, curp, esrc);
  // h0 + HT + adjacency (MFMA path)
  k_seq<<<1024, blk, 0, stream>>>(inp, Wseq, bseq, h);
  k_tr<<<1024, blk, 0, stream>>>(h, HT);
  k_castSE<<<256, blk, 0, stream>>>(SE, SEh);
  k_castTE<<<64, blk, 0, stream>>>(TE, TEh);
  k_adjmm<<<dim3(32, 32), blk, 0, stream>>>(SEh, TEh, Af, Zpart);
  k_rowz<<<16, blk, 0, stream>>>(Zpart, rowZ);
  k_scaleA<<<8192, blk, 0, stream>>>(Af, rowZ);
  // ---- layer 0 ----
  k_gemm<<<1024, blk, 0, stream>>>(Af, HT, adp);
  k_comb0<<<1024, blk, 0, stream>>>(h, adp, Wl[0], bl[0], Wo, bo, h);
  k_tr<<<1024, blk, 0, stream>>>(h, HT);
  // ---- layer 1 ----
  k_xp<3><<<1024, blk, 0, stream>>>(h, Wg[1], xp);
  k_dots<3><<<16384, blk, 0, stream>>>(xp, asrc[1], adst[1], als, ald);
  k_gemm<<<1024, blk, 0, stream>>>(Af, HT, adp);
  k_agg<3><<<16384, blk, 0, stream>>>(xp, als, ald, offs, cnt, esrc, bgp[1], hcur);
  k_comb12<0><<<1024, blk, 0, stream>>>(h, adp, hcur, Wl[1], bl[1], h);
  k_tr<<<1024, blk, 0, stream>>>(h, HT);
  // ---- layer 2 ----
  k_xp<1><<<1024, blk, 0, stream>>>(h, Wg[2], xp);
  k_dots<1><<<16384, blk, 0, stream>>>(xp, asrc[2], adst[2], als, ald);
  k_gemm<<<1024, blk, 0, stream>>>(Af, HT, adp);
  k_agg<1><<<16384, blk, 0, stream>>>(xp, als, ald, offs, cnt, esrc, bgp[2], hcur);
  k_comb12<1><<<1024, blk, 0, stream>>>(h, adp, hcur, Wl[2], bl[2], out);
}